// Round 2
// baseline (3751.344 us; speedup 1.0000x reference)
//
#include <hip/hip_runtime.h>
#include <math.h>

#define NEG_SLOPE 0.2f

// ---------- helpers ----------
__device__ __forceinline__ unsigned enc_f(float f) {
    unsigned b = __float_as_uint(f);
    return (b & 0x80000000u) ? ~b : (b | 0x80000000u);
}
__device__ __forceinline__ float dec_f(unsigned k) {
    unsigned b = (k & 0x80000000u) ? (k & 0x7FFFFFFFu) : ~k;
    return __uint_as_float(b);
}
__device__ __forceinline__ void atomAddF(float* p, float v) {
    unsafeAtomicAdd(p, v);   // HW global_atomic_add_f32 on gfx950
}

// ---------- RGAT kernels ----------
// Vsrc[r*64+d] = sum_e W[r,d,e]*a_src[r,e];  Vdst analogous.
__global__ void compute_v_kernel(const float* __restrict__ W,
                                 const float* __restrict__ a_src,
                                 const float* __restrict__ a_dst,
                                 float* __restrict__ Vsrc, float* __restrict__ Vdst,
                                 int R) {
    int idx = blockIdx.x * blockDim.x + threadIdx.x;   // r*64+d
    if (idx >= R * 64) return;
    int r = idx >> 6;
    const float* Wr = W + idx * 64;            // row (r,d,:)
    const float* as = a_src + r * 64;
    const float* ad = a_dst + r * 64;
    float s = 0.f, t = 0.f;
    for (int e = 0; e < 64; e++) { float w = Wr[e]; s = fmaf(w, as[e], s); t = fmaf(w, ad[e], t); }
    Vsrc[idx] = s; Vdst[idx] = t;
}

// attS[n*R+r] = h[n,:] . Vsrc[r,:]   (one wave per node)
__global__ void node_att_kernel(const float* __restrict__ h,
                                const float* __restrict__ Vsrc,
                                const float* __restrict__ Vdst,
                                float* __restrict__ attS, float* __restrict__ attD,
                                int N, int R) {
    int wave = (blockIdx.x * blockDim.x + threadIdx.x) >> 6;
    int lane = threadIdx.x & 63;
    if (wave >= N) return;
    float x = h[wave * 64 + lane];
    for (int r = 0; r < R; r++) {
        float s = x * Vsrc[r * 64 + lane];
        float t = x * Vdst[r * 64 + lane];
        for (int o = 32; o; o >>= 1) { s += __shfl_xor(s, o); t += __shfl_xor(t, o); }
        if (lane == 0) { attS[wave * R + r] = s; attD[wave * R + r] = t; }
    }
}

__global__ void init_seg_kernel(unsigned* __restrict__ segmax, float* __restrict__ segsum, int N) {
    int i = blockIdx.x * blockDim.x + threadIdx.x;
    if (i < N) { segmax[i] = enc_f(-INFINITY); segsum[i] = 0.f; }
}

__global__ void edge_score_kernel(const int* __restrict__ src, const int* __restrict__ dst,
                                  const int* __restrict__ rel,
                                  const float* __restrict__ attS, const float* __restrict__ attD,
                                  float* __restrict__ scores, unsigned* __restrict__ segmax,
                                  int E, int R) {
    int e = blockIdx.x * blockDim.x + threadIdx.x;
    if (e >= E) return;
    int r = rel[e];
    float sc = attS[src[e] * R + r] + attD[dst[e] * R + r];
    sc = sc > 0.f ? sc : NEG_SLOPE * sc;
    scores[e] = sc;
    atomicMax(&segmax[dst[e]], enc_f(sc));
}

// in-place: scores[e] <- exp(scores[e]-max); accumulate segsum
__global__ void edge_exp_kernel(const int* __restrict__ dst, float* __restrict__ scores,
                                const unsigned* __restrict__ segmax, float* __restrict__ segsum,
                                int E) {
    int e = blockIdx.x * blockDim.x + threadIdx.x;
    if (e >= E) return;
    int d = dst[e];
    float ex = expf(scores[e] - dec_f(segmax[d]));
    scores[e] = ex;
    atomAddF(&segsum[d], ex);
}

// hW[rl, n, :] = h[n,:] @ W[r0+rl]   -- one wave per 64 nodes per relation.
// Lane j holds W column j in 64 VGPRs (loaded once); h row is wave-uniform
// (scalar loads) -> inner loop is 64 v_fmac with SGPR operand: compute-bound.
__global__ void hw_gemm_kernel(const float* __restrict__ h, const float* __restrict__ W,
                               float* __restrict__ hW, int N, int r0) {
    int lane = threadIdx.x & 63;
    int wv   = (blockIdx.x * blockDim.x + threadIdx.x) >> 6;  // wave id over grid.x
    int rl   = blockIdx.y;
    int nodeBase = wv * 64;
    if (nodeBase >= N) return;
    const float* Wr = W + (size_t)(r0 + rl) * 4096;
    float vW[64];
#pragma unroll
    for (int k = 0; k < 64; k++) vW[k] = Wr[k * 64 + lane];
    int nEnd = min(nodeBase + 64, N);
    for (int node = nodeBase; node < nEnd; node++) {
        const float* hrow = h + (size_t)node * 64;   // wave-uniform address
        float acc = 0.f;
#pragma unroll
        for (int k = 0; k < 64; k++) acc = fmaf(hrow[k], vW[k], acc);
        hW[((size_t)rl * N + node) * 64 + lane] = acc;
    }
}

// agg[dst] += alpha * hW[rel, src]  (edges with rel in [r0,r1); wave per edge)
__global__ void edge_add_kernel(const int* __restrict__ src, const int* __restrict__ dst,
                                const int* __restrict__ rel, const float* __restrict__ ex,
                                const float* __restrict__ segsum, const float* __restrict__ hW,
                                float* __restrict__ agg, int E, int N, int r0, int r1) {
    int g = blockIdx.x * blockDim.x + threadIdx.x;
    int e = g >> 6, lane = g & 63;
    if (e >= E) return;
    int r = rel[e];                    // wave-uniform
    if (r < r0 || r >= r1) return;
    int d = dst[e];
    float alpha = ex[e] / (segsum[d] + 1e-9f);
    float v = hW[((size_t)(r - r0) * N + src[e]) * 64 + lane] * alpha;
    atomAddF(&agg[(size_t)d * 64 + lane], v);
}

__global__ void elu_kernel(float* __restrict__ x, int n) {
    int i = blockIdx.x * blockDim.x + threadIdx.x;
    if (i < n) { float v = x[i]; x[i] = v > 0.f ? v : expm1f(v); }
}

// out[seg[n]*64+d] += h[n*64+d]
__global__ void seg_sum64_kernel(const float* __restrict__ h, const int* __restrict__ seg,
                                 float* __restrict__ out, int N) {
    int i = blockIdx.x * blockDim.x + threadIdx.x;
    if (i >= N * 64) return;
    int n = i >> 6, d = i & 63;
    atomAddF(&out[seg[n] * 64 + d], h[i]);
}

// feat[b,0:64] += molr[m]; feat[b,64:128] += mol[m]
__global__ void readout_kernel(const float* __restrict__ molr, const float* __restrict__ mol,
                               const int* __restrict__ mol2rxn, float* __restrict__ feat, int M) {
    int i = blockIdx.x * blockDim.x + threadIdx.x;
    if (i >= M * 64) return;
    int m = i >> 6, d = i & 63;
    int b = mol2rxn[m];
    atomAddF(&feat[b * 128 + d], molr[i]);
    atomAddF(&feat[b * 128 + 64 + d], mol[i]);
}

// hm[b,j] = PReLU(feat[b,:] @ w_fc1[:,j] + b_fc1[j])  (block=512, grid=1024)
__global__ void fc1_kernel(const float* __restrict__ feat, const float* __restrict__ w,
                           const float* __restrict__ bias, const float* __restrict__ prelu,
                           float* __restrict__ hm) {
    __shared__ float f[128];
    int b = blockIdx.x, j = threadIdx.x;
    if (j < 128) f[j] = feat[b * 128 + j];
    __syncthreads();
    float acc = bias[j];
#pragma unroll 8
    for (int k = 0; k < 128; k++) acc = fmaf(f[k], w[k * 512 + j], acc);
    float p = *prelu;
    hm[b * 512 + j] = acc > 0.f ? acc : p * acc;
}

// out[b,o] = hm[b,:] @ w_fc2[:,o] + b_fc2[o]
__global__ void fc2_kernel(const float* __restrict__ hm, const float* __restrict__ w,
                           const float* __restrict__ bias, float* __restrict__ out) {
    __shared__ float f[512];
    int b = blockIdx.y;
    int j = blockIdx.x * blockDim.x + threadIdx.x;
    for (int k = threadIdx.x; k < 512; k += blockDim.x) f[k] = hm[b * 512 + k];
    __syncthreads();
    if (j >= 703) return;
    float acc = bias[j];
    for (int k = 0; k < 512; k++) acc = fmaf(f[k], w[k * 703 + j], acc);
    out[b * 703 + j] = acc;
}

// ---------- launch ----------
extern "C" void kernel_launch(void* const* d_in, const int* in_sizes, int n_in,
                              void* d_out, int out_size, void* d_ws, size_t ws_size,
                              hipStream_t stream) {
    const float* node_feats = (const float*)d_in[0];
    const int*   edge_src   = (const int*)d_in[1];
    const int*   edge_dst   = (const int*)d_in[2];
    const int*   edge_rel   = (const int*)d_in[3];
    const int*   node2mol   = (const int*)d_in[4];
    const int*   rxn_src    = (const int*)d_in[5];
    const int*   rxn_dst    = (const int*)d_in[6];
    const int*   rxn_rel    = (const int*)d_in[7];
    const int*   mol2rxn    = (const int*)d_in[8];
    const float* W1     = (const float*)d_in[9];
    const float* a_src1 = (const float*)d_in[10];
    const float* a_dst1 = (const float*)d_in[11];
    const float* W2     = (const float*)d_in[12];
    const float* a_src2 = (const float*)d_in[13];
    const float* a_dst2 = (const float*)d_in[14];
    const float* Wr     = (const float*)d_in[15];
    const float* a_srcr = (const float*)d_in[16];
    const float* a_dstr = (const float*)d_in[17];
    const float* w_fc1  = (const float*)d_in[18];
    const float* b_fc1  = (const float*)d_in[19];
    const float* prelu1 = (const float*)d_in[20];
    const float* w_fc2  = (const float*)d_in[21];
    const float* b_fc2  = (const float*)d_in[22];

    const int N = 100000, E = 800000, M = 5000, ER = 40000;

    float* ws = (float*)d_ws;
    float* h1     = ws;                    // 6,400,000
    float* h2     = h1 + 6400000;          // 6,400,000
    float* attS   = h2 + 6400000;          // 800,000
    float* attD   = attS + 800000;         // 800,000
    float* scores = attD + 800000;         // 800,000
    unsigned* segmax = (unsigned*)(scores + 800000);  // 100,000
    float* segsum = (float*)(segmax + 100000);        // 100,000
    float* mol    = segsum + 100000;       // 320,000
    float* molr   = mol + 320000;          // 320,000
    float* feat   = molr + 320000;         // 131,072
    float* hm     = feat + 131072;         // 524,288
    float* Vsrc   = hm + 524288;           // 512
    float* Vdst   = Vsrc + 512;            // 512
    float* hWbuf  = Vdst + 512;            // up to 8*N*64 = 51.2M floats (chunked by ws_size)

    size_t usedFloats = (size_t)(hWbuf - ws);
    size_t availFloats = (ws_size / 4 > usedFloats) ? (ws_size / 4 - usedFloats) : 0;

    auto rgat = [&](const float* hin, int n, int e, const int* es, const int* ed,
                    const int* er, const float* W, const float* as, const float* ad,
                    float* agg, int R) {
        compute_v_kernel<<<dim3((R * 64 + 63) / 64), 64, 0, stream>>>(W, as, ad, Vsrc, Vdst, R);
        node_att_kernel<<<dim3((n * 64 + 255) / 256), 256, 0, stream>>>(hin, Vsrc, Vdst, attS, attD, n, R);
        init_seg_kernel<<<dim3((n + 255) / 256), 256, 0, stream>>>(segmax, segsum, n);
        edge_score_kernel<<<dim3((e + 255) / 256), 256, 0, stream>>>(es, ed, er, attS, attD, scores, segmax, e, R);
        edge_exp_kernel<<<dim3((e + 255) / 256), 256, 0, stream>>>(ed, scores, segmax, segsum, e);
        hipMemsetAsync(agg, 0, (size_t)n * 64 * sizeof(float), stream);

        size_t perRel = (size_t)n * 64;
        int chunk = (int)(availFloats / perRel);
        if (chunk < 1) chunk = 1;
        if (chunk > R) chunk = R;
        for (int r0 = 0; r0 < R; r0 += chunk) {
            int r1 = r0 + chunk; if (r1 > R) r1 = R;
            hw_gemm_kernel<<<dim3((n + 255) / 256, r1 - r0), 256, 0, stream>>>(hin, W, hWbuf, n, r0);
            edge_add_kernel<<<dim3(((size_t)e * 64 + 255) / 256), 256, 0, stream>>>(
                es, ed, er, scores, segsum, hWbuf, agg, e, n, r0, r1);
        }
        elu_kernel<<<dim3((n * 64 + 255) / 256), 256, 0, stream>>>(agg, n * 64);
    };

    // atom-level RGAT x2
    rgat(node_feats, N, E, edge_src, edge_dst, edge_rel, W1, a_src1, a_dst1, h1, 8);
    rgat(h1,         N, E, edge_src, edge_dst, edge_rel, W2, a_src2, a_dst2, h2, 8);

    // molecule pooling
    hipMemsetAsync(mol, 0, (size_t)M * 64 * sizeof(float), stream);
    seg_sum64_kernel<<<dim3((N * 64 + 255) / 256), 256, 0, stream>>>(h2, node2mol, mol, N);

    // reaction-graph RGAT
    rgat(mol, M, ER, rxn_src, rxn_dst, rxn_rel, Wr, a_srcr, a_dstr, molr, 4);

    // reaction readout
    hipMemsetAsync(feat, 0, (size_t)1024 * 128 * sizeof(float), stream);
    readout_kernel<<<dim3((M * 64 + 255) / 256), 256, 0, stream>>>(molr, mol, mol2rxn, feat, M);

    // MLP head
    fc1_kernel<<<dim3(1024), 512, 0, stream>>>(feat, w_fc1, b_fc1, prelu1, hm);
    fc2_kernel<<<dim3(3, 1024), 256, 0, stream>>>(hm, w_fc2, b_fc2, (float*)d_out);
}

// Round 3
// 1389.349 us; speedup vs baseline: 2.7001x; 2.7001x over previous
//
#include <hip/hip_runtime.h>
#include <math.h>

#define NEG_SLOPE 0.2f

// ---------- helpers ----------
__device__ __forceinline__ unsigned enc_f(float f) {
    unsigned b = __float_as_uint(f);
    return (b & 0x80000000u) ? ~b : (b | 0x80000000u);
}
__device__ __forceinline__ float dec_f(unsigned k) {
    unsigned b = (k & 0x80000000u) ? (k & 0x7FFFFFFFu) : ~k;
    return __uint_as_float(b);
}
__device__ __forceinline__ void atomAddF(float* p, float v) {
    unsafeAtomicAdd(p, v);   // HW global_atomic_add_f32 on gfx950
}

// ---------- RGAT kernels ----------
// Vsrc[r*64+d] = sum_e W[r,d,e]*a_src[r,e];  Vdst analogous.
__global__ void compute_v_kernel(const float* __restrict__ W,
                                 const float* __restrict__ a_src,
                                 const float* __restrict__ a_dst,
                                 float* __restrict__ Vsrc, float* __restrict__ Vdst,
                                 int R) {
    int idx = blockIdx.x * blockDim.x + threadIdx.x;   // r*64+d
    if (idx >= R * 64) return;
    int r = idx >> 6;
    const float* Wr = W + idx * 64;            // row (r,d,:)
    const float* as = a_src + r * 64;
    const float* ad = a_dst + r * 64;
    float s = 0.f, t = 0.f;
    for (int e = 0; e < 64; e++) { float w = Wr[e]; s = fmaf(w, as[e], s); t = fmaf(w, ad[e], t); }
    Vsrc[idx] = s; Vdst[idx] = t;
}

// attS[n*R+r] = h[n,:] . Vsrc[r,:]   (one wave per node)
__global__ void node_att_kernel(const float* __restrict__ h,
                                const float* __restrict__ Vsrc,
                                const float* __restrict__ Vdst,
                                float* __restrict__ attS, float* __restrict__ attD,
                                int N, int R) {
    int wave = (blockIdx.x * blockDim.x + threadIdx.x) >> 6;
    int lane = threadIdx.x & 63;
    if (wave >= N) return;
    float x = h[wave * 64 + lane];
    for (int r = 0; r < R; r++) {
        float s = x * Vsrc[r * 64 + lane];
        float t = x * Vdst[r * 64 + lane];
        for (int o = 32; o; o >>= 1) { s += __shfl_xor(s, o); t += __shfl_xor(t, o); }
        if (lane == 0) { attS[wave * R + r] = s; attD[wave * R + r] = t; }
    }
}

__global__ void init_seg_kernel(unsigned* __restrict__ segmax, float* __restrict__ segsum, int N) {
    int i = blockIdx.x * blockDim.x + threadIdx.x;
    if (i < N) { segmax[i] = enc_f(-INFINITY); segsum[i] = 0.f; }
}

__global__ void edge_score_kernel(const int* __restrict__ src, const int* __restrict__ dst,
                                  const int* __restrict__ rel,
                                  const float* __restrict__ attS, const float* __restrict__ attD,
                                  float* __restrict__ scores, unsigned* __restrict__ segmax,
                                  int E, int R) {
    int e = blockIdx.x * blockDim.x + threadIdx.x;
    if (e >= E) return;
    int r = rel[e];
    float sc = attS[src[e] * R + r] + attD[dst[e] * R + r];
    sc = sc > 0.f ? sc : NEG_SLOPE * sc;
    scores[e] = sc;
    atomicMax(&segmax[dst[e]], enc_f(sc));
}

// in-place: scores[e] <- exp(scores[e]-max); accumulate segsum
__global__ void edge_exp_kernel(const int* __restrict__ dst, float* __restrict__ scores,
                                const unsigned* __restrict__ segmax, float* __restrict__ segsum,
                                int E) {
    int e = blockIdx.x * blockDim.x + threadIdx.x;
    if (e >= E) return;
    int d = dst[e];
    float ex = expf(scores[e] - dec_f(segmax[d]));
    scores[e] = ex;
    atomAddF(&segsum[d], ex);
}

// hW[rl, n, e] = sum_d h[n,d] * W[r0+rl, d, e]
// LDS-tiled fp32 GEMM: 64-node x 64-dim tile per block, 4x4 register micro-tile
// per thread (16 acc VGPRs -- no spill, unlike the vW[64] version).
#define HPAD 68   // h-tile LDS row stride (words): 2-way bank aliasing only
__global__ __launch_bounds__(256) void hw_gemm_kernel(
        const float* __restrict__ h, const float* __restrict__ W,
        float* __restrict__ hW, int N, int r0) {
    __shared__ float Wl[64 * 64];     // [d][e] -- same layout as global
    __shared__ float hl[64 * HPAD];   // [node][d], padded
    int t = threadIdx.x;
    int nodeBase = blockIdx.x * 64;
    int r = r0 + blockIdx.y;

    // stage W[r]: 4096 floats via float4
    {
        const float4* Wg = (const float4*)(W + (size_t)r * 4096);
        float4* Wl4 = (float4*)Wl;
#pragma unroll
        for (int i = 0; i < 4; i++) Wl4[t + i * 256] = Wg[t + i * 256];
    }
    // stage h tile: 64 rows x 16 float4
    {
        const float4* hg = (const float4*)h;
#pragma unroll
        for (int i = 0; i < 4; i++) {
            int idx = t + i * 256;          // 0..1023
            int row = idx >> 4, col4 = idx & 15;
            int node = nodeBase + row;
            float4 v = (node < N) ? hg[(size_t)node * 16 + col4] : float4{0.f, 0.f, 0.f, 0.f};
            float* p = &hl[row * HPAD + col4 * 4];
            p[0] = v.x; p[1] = v.y; p[2] = v.z; p[3] = v.w;
        }
    }
    __syncthreads();

    int e4 = (t & 15) * 4;
    int n4 = (t >> 4) * 4;
    float acc[4][4] = {};
    for (int d = 0; d < 64; d += 4) {
        float4 wv[4], hv[4];
#pragma unroll
        for (int dd = 0; dd < 4; dd++) wv[dd] = *(const float4*)&Wl[(d + dd) * 64 + e4];
#pragma unroll
        for (int i = 0; i < 4; i++) hv[i] = *(const float4*)&hl[(n4 + i) * HPAD + d];
#pragma unroll
        for (int i = 0; i < 4; i++) {
            const float hvv[4] = {hv[i].x, hv[i].y, hv[i].z, hv[i].w};
#pragma unroll
            for (int dd = 0; dd < 4; dd++) {
                const float* wp = (const float*)&wv[dd];
#pragma unroll
                for (int j = 0; j < 4; j++) acc[i][j] = fmaf(hvv[dd], wp[j], acc[i][j]);
            }
        }
    }
    size_t rowBase = (size_t)blockIdx.y * N;
#pragma unroll
    for (int i = 0; i < 4; i++) {
        int node = nodeBase + n4 + i;
        if (node < N) {
            float4 v = {acc[i][0], acc[i][1], acc[i][2], acc[i][3]};
            *(float4*)&hW[(rowBase + node) * 64 + e4] = v;
        }
    }
}

// agg[dst] += alpha * hW[rel, src]  (edges with rel in [r0,r1); wave per edge)
__global__ void edge_add_kernel(const int* __restrict__ src, const int* __restrict__ dst,
                                const int* __restrict__ rel, const float* __restrict__ ex,
                                const float* __restrict__ segsum, const float* __restrict__ hW,
                                float* __restrict__ agg, int E, int N, int r0, int r1) {
    int g = blockIdx.x * blockDim.x + threadIdx.x;
    int e = g >> 6, lane = g & 63;
    if (e >= E) return;
    int r = rel[e];                    // wave-uniform
    if (r < r0 || r >= r1) return;
    int d = dst[e];
    float alpha = ex[e] / (segsum[d] + 1e-9f);
    float v = hW[((size_t)(r - r0) * N + src[e]) * 64 + lane] * alpha;
    atomAddF(&agg[(size_t)d * 64 + lane], v);
}

__global__ void elu_kernel(float* __restrict__ x, int n) {
    int i = blockIdx.x * blockDim.x + threadIdx.x;
    if (i < n) { float v = x[i]; x[i] = v > 0.f ? v : expm1f(v); }
}

// out[seg[n]*64+d] += h[n*64+d]
__global__ void seg_sum64_kernel(const float* __restrict__ h, const int* __restrict__ seg,
                                 float* __restrict__ out, int N) {
    int i = blockIdx.x * blockDim.x + threadIdx.x;
    if (i >= N * 64) return;
    int n = i >> 6, d = i & 63;
    atomAddF(&out[seg[n] * 64 + d], h[i]);
}

// feat[b,0:64] += molr[m]; feat[b,64:128] += mol[m]
__global__ void readout_kernel(const float* __restrict__ molr, const float* __restrict__ mol,
                               const int* __restrict__ mol2rxn, float* __restrict__ feat, int M) {
    int i = blockIdx.x * blockDim.x + threadIdx.x;
    if (i >= M * 64) return;
    int m = i >> 6, d = i & 63;
    int b = mol2rxn[m];
    atomAddF(&feat[b * 128 + d], molr[i]);
    atomAddF(&feat[b * 128 + 64 + d], mol[i]);
}

// hm[b,j] = PReLU(feat[b,:] @ w_fc1[:,j] + b_fc1[j])  (block=512, grid=1024)
__global__ void fc1_kernel(const float* __restrict__ feat, const float* __restrict__ w,
                           const float* __restrict__ bias, const float* __restrict__ prelu,
                           float* __restrict__ hm) {
    __shared__ float f[128];
    int b = blockIdx.x, j = threadIdx.x;
    if (j < 128) f[j] = feat[b * 128 + j];
    __syncthreads();
    float acc = bias[j];
#pragma unroll 8
    for (int k = 0; k < 128; k++) acc = fmaf(f[k], w[k * 512 + j], acc);
    float p = *prelu;
    hm[b * 512 + j] = acc > 0.f ? acc : p * acc;
}

// out[b,o] = hm[b,:] @ w_fc2[:,o] + b_fc2[o]
__global__ void fc2_kernel(const float* __restrict__ hm, const float* __restrict__ w,
                           const float* __restrict__ bias, float* __restrict__ out) {
    __shared__ float f[512];
    int b = blockIdx.y;
    int j = blockIdx.x * blockDim.x + threadIdx.x;
    for (int k = threadIdx.x; k < 512; k += blockDim.x) f[k] = hm[b * 512 + k];
    __syncthreads();
    if (j >= 703) return;
    float acc = bias[j];
    for (int k = 0; k < 512; k++) acc = fmaf(f[k], w[k * 703 + j], acc);
    out[b * 703 + j] = acc;
}

// ---------- launch ----------
extern "C" void kernel_launch(void* const* d_in, const int* in_sizes, int n_in,
                              void* d_out, int out_size, void* d_ws, size_t ws_size,
                              hipStream_t stream) {
    const float* node_feats = (const float*)d_in[0];
    const int*   edge_src   = (const int*)d_in[1];
    const int*   edge_dst   = (const int*)d_in[2];
    const int*   edge_rel   = (const int*)d_in[3];
    const int*   node2mol   = (const int*)d_in[4];
    const int*   rxn_src    = (const int*)d_in[5];
    const int*   rxn_dst    = (const int*)d_in[6];
    const int*   rxn_rel    = (const int*)d_in[7];
    const int*   mol2rxn    = (const int*)d_in[8];
    const float* W1     = (const float*)d_in[9];
    const float* a_src1 = (const float*)d_in[10];
    const float* a_dst1 = (const float*)d_in[11];
    const float* W2     = (const float*)d_in[12];
    const float* a_src2 = (const float*)d_in[13];
    const float* a_dst2 = (const float*)d_in[14];
    const float* Wr     = (const float*)d_in[15];
    const float* a_srcr = (const float*)d_in[16];
    const float* a_dstr = (const float*)d_in[17];
    const float* w_fc1  = (const float*)d_in[18];
    const float* b_fc1  = (const float*)d_in[19];
    const float* prelu1 = (const float*)d_in[20];
    const float* w_fc2  = (const float*)d_in[21];
    const float* b_fc2  = (const float*)d_in[22];

    const int N = 100000, E = 800000, M = 5000, ER = 40000;

    float* ws = (float*)d_ws;
    float* h1     = ws;                    // 6,400,000
    float* h2     = h1 + 6400000;          // 6,400,000
    float* attS   = h2 + 6400000;          // 800,000
    float* attD   = attS + 800000;         // 800,000
    float* scores = attD + 800000;         // 800,000
    unsigned* segmax = (unsigned*)(scores + 800000);  // 100,000
    float* segsum = (float*)(segmax + 100000);        // 100,000
    float* mol    = segsum + 100000;       // 320,000
    float* molr   = mol + 320000;          // 320,000
    float* feat   = molr + 320000;         // 131,072
    float* hm     = feat + 131072;         // 524,288
    float* Vsrc   = hm + 524288;           // 512
    float* Vdst   = Vsrc + 512;            // 512
    float* hWbuf  = Vdst + 512;            // up to 8*N*64 floats (chunked by ws_size)

    size_t usedFloats = (size_t)(hWbuf - ws);
    size_t availFloats = (ws_size / 4 > usedFloats) ? (ws_size / 4 - usedFloats) : 0;

    auto rgat = [&](const float* hin, int n, int e, const int* es, const int* ed,
                    const int* er, const float* W, const float* as, const float* ad,
                    float* agg, int R) {
        compute_v_kernel<<<dim3((R * 64 + 63) / 64), 64, 0, stream>>>(W, as, ad, Vsrc, Vdst, R);
        node_att_kernel<<<dim3((n * 64 + 255) / 256), 256, 0, stream>>>(hin, Vsrc, Vdst, attS, attD, n, R);
        init_seg_kernel<<<dim3((n + 255) / 256), 256, 0, stream>>>(segmax, segsum, n);
        edge_score_kernel<<<dim3((e + 255) / 256), 256, 0, stream>>>(es, ed, er, attS, attD, scores, segmax, e, R);
        edge_exp_kernel<<<dim3((e + 255) / 256), 256, 0, stream>>>(ed, scores, segmax, segsum, e);
        hipMemsetAsync(agg, 0, (size_t)n * 64 * sizeof(float), stream);

        size_t perRel = (size_t)n * 64;
        int chunk = (int)(availFloats / perRel);
        if (chunk < 1) chunk = 1;
        if (chunk > R) chunk = R;
        for (int r0 = 0; r0 < R; r0 += chunk) {
            int r1 = r0 + chunk; if (r1 > R) r1 = R;
            hw_gemm_kernel<<<dim3((n + 63) / 64, r1 - r0), 256, 0, stream>>>(hin, W, hWbuf, n, r0);
            edge_add_kernel<<<dim3(((size_t)e * 64 + 255) / 256), 256, 0, stream>>>(
                es, ed, er, scores, segsum, hWbuf, agg, e, n, r0, r1);
        }
        elu_kernel<<<dim3((n * 64 + 255) / 256), 256, 0, stream>>>(agg, n * 64);
    };

    // atom-level RGAT x2
    rgat(node_feats, N, E, edge_src, edge_dst, edge_rel, W1, a_src1, a_dst1, h1, 8);
    rgat(h1,         N, E, edge_src, edge_dst, edge_rel, W2, a_src2, a_dst2, h2, 8);

    // molecule pooling
    hipMemsetAsync(mol, 0, (size_t)M * 64 * sizeof(float), stream);
    seg_sum64_kernel<<<dim3((N * 64 + 255) / 256), 256, 0, stream>>>(h2, node2mol, mol, N);

    // reaction-graph RGAT
    rgat(mol, M, ER, rxn_src, rxn_dst, rxn_rel, Wr, a_srcr, a_dstr, molr, 4);

    // reaction readout
    hipMemsetAsync(feat, 0, (size_t)1024 * 128 * sizeof(float), stream);
    readout_kernel<<<dim3((M * 64 + 255) / 256), 256, 0, stream>>>(molr, mol, mol2rxn, feat, M);

    // MLP head
    fc1_kernel<<<dim3(1024), 512, 0, stream>>>(feat, w_fc1, b_fc1, prelu1, hm);
    fc2_kernel<<<dim3(3, 1024), 256, 0, stream>>>(hm, w_fc2, b_fc2, (float*)d_out);
}

// Round 4
// 1223.937 us; speedup vs baseline: 3.0650x; 1.1351x over previous
//
#include <hip/hip_runtime.h>
#include <math.h>

#define NEG_SLOPE 0.2f

__device__ __forceinline__ void atomAddF(float* p, float v) {
    unsafeAtomicAdd(p, v);   // HW global_atomic_add_f32 on gfx950
}

// ================= CSR build (counting sort by dst) =================
__global__ void hist_kernel(const int* __restrict__ dst, int* __restrict__ cnt, int E) {
    int e = blockIdx.x * blockDim.x + threadIdx.x;
    if (e < E) atomicAdd(&cnt[dst[e]], 1);
}

// per-256-block inclusive scan; block totals to bsum
__global__ void scan1_kernel(const int* __restrict__ cnt, int* __restrict__ incl,
                             int* __restrict__ bsum, int n) {
    __shared__ int s[256];
    int t = threadIdx.x, i = blockIdx.x * 256 + t;
    int v = (i < n) ? cnt[i] : 0;
    s[t] = v; __syncthreads();
    for (int o = 1; o < 256; o <<= 1) {
        int u = (t >= o) ? s[t - o] : 0;
        __syncthreads(); s[t] += u; __syncthreads();
    }
    if (i < n) incl[i] = s[t];
    if (t == 255) bsum[blockIdx.x] = s[255];
}

// exclusive scan of block sums (nb <= 512)
__global__ void scan2_kernel(int* __restrict__ bsum, int nb) {
    __shared__ int s[512];
    int t = threadIdx.x;
    int v = (t < nb) ? bsum[t] : 0;
    s[t] = v; __syncthreads();
    for (int o = 1; o < 512; o <<= 1) {
        int u = (t >= o) ? s[t - o] : 0;
        __syncthreads(); s[t] += u; __syncthreads();
    }
    if (t < nb) bsum[t] = s[t] - v;   // exclusive
}

// rowptr = exclusive scan; cursor = copy; rowptr[n] = E
__global__ void scan3_kernel(const int* __restrict__ incl, const int* __restrict__ cnt,
                             const int* __restrict__ bsum, int* __restrict__ rowptr,
                             int* __restrict__ cursor, int n, int E) {
    int i = blockIdx.x * blockDim.x + threadIdx.x;
    if (i < n) {
        int v = incl[i] - cnt[i] + bsum[i >> 8];
        rowptr[i] = v; cursor[i] = v;
    } else if (i == n) {
        rowptr[n] = E;
    }
}

__global__ void scatter_kernel(const int* __restrict__ dst, int* __restrict__ cursor,
                               int* __restrict__ perm, int E) {
    int e = blockIdx.x * blockDim.x + threadIdx.x;
    if (e < E) { int pos = atomicAdd(&cursor[dst[e]], 1); perm[pos] = e; }
}

// ================= RGAT =================
// Vsrc[r*64+d] = sum_e W[r,d,e]*a_src[r,e];  Vdst analogous.
__global__ void compute_v_kernel(const float* __restrict__ W,
                                 const float* __restrict__ a_src,
                                 const float* __restrict__ a_dst,
                                 float* __restrict__ Vsrc, float* __restrict__ Vdst,
                                 int R) {
    int idx = blockIdx.x * blockDim.x + threadIdx.x;   // r*64+d
    if (idx >= R * 64) return;
    int r = idx >> 6;
    const float* Wr = W + idx * 64;
    const float* as = a_src + r * 64;
    const float* ad = a_dst + r * 64;
    float s = 0.f, t = 0.f;
    for (int e = 0; e < 64; e++) { float w = Wr[e]; s = fmaf(w, as[e], s); t = fmaf(w, ad[e], t); }
    Vsrc[idx] = s; Vdst[idx] = t;
}

// attS[n*R+r] = h[n,:] . Vsrc[r,:]   (one wave per node)
__global__ void node_att_kernel(const float* __restrict__ h,
                                const float* __restrict__ Vsrc,
                                const float* __restrict__ Vdst,
                                float* __restrict__ attS, float* __restrict__ attD,
                                int N, int R) {
    int wave = (blockIdx.x * blockDim.x + threadIdx.x) >> 6;
    int lane = threadIdx.x & 63;
    if (wave >= N) return;
    float x = h[(size_t)wave * 64 + lane];
    for (int r = 0; r < R; r++) {
        float s = x * Vsrc[r * 64 + lane];
        float t = x * Vdst[r * 64 + lane];
        for (int o = 32; o; o >>= 1) { s += __shfl_xor(s, o); t += __shfl_xor(t, o); }
        if (lane == 0) { attS[wave * R + r] = s; attD[wave * R + r] = t; }
    }
}

// fused per-dst softmax: alphaS[i] (CSR order) = normalized attention weight
__global__ __launch_bounds__(256) void alpha_kernel(
        const int* __restrict__ rowptr, const int* __restrict__ perm,
        const int* __restrict__ src, const int* __restrict__ rel,
        const float* __restrict__ attS, const float* __restrict__ attD,
        float* __restrict__ alphaS, int n, int R) {
    int g = blockIdx.x * blockDim.x + threadIdx.x;
    int wv = g >> 6, lane = g & 63;
    if (wv >= n) return;
    int start = rowptr[wv], end = rowptr[wv + 1];
    int deg = end - start;
    if (deg <= 0) return;
    if (deg <= 64) {
        int i = start + lane;
        bool act = i < end;
        float s = -INFINITY;
        if (act) {
            int e = perm[i]; int r = rel[e];
            float sc = attS[src[e] * R + r] + attD[wv * R + r];
            s = sc > 0.f ? sc : NEG_SLOPE * sc;
        }
        float m = s;
        for (int o = 32; o; o >>= 1) m = fmaxf(m, __shfl_xor(m, o));
        float ex = act ? expf(s - m) : 0.f;
        float sum = ex;
        for (int o = 32; o; o >>= 1) sum += __shfl_xor(sum, o);
        float inv = 1.f / (sum + 1e-9f);
        if (act) alphaS[i] = ex * inv;
    } else {
        float m = -INFINITY;
        for (int base = start; base < end; base += 64) {
            int i = base + lane;
            if (i < end) {
                int e = perm[i]; int r = rel[e];
                float sc = attS[src[e] * R + r] + attD[wv * R + r];
                sc = sc > 0.f ? sc : NEG_SLOPE * sc;
                alphaS[i] = sc;
                m = fmaxf(m, sc);
            }
        }
        for (int o = 32; o; o >>= 1) m = fmaxf(m, __shfl_xor(m, o));
        float sum = 0.f;
        for (int base = start; base < end; base += 64) {
            int i = base + lane;
            if (i < end) { float ex = expf(alphaS[i] - m); alphaS[i] = ex; sum += ex; }
        }
        for (int o = 32; o; o >>= 1) sum += __shfl_xor(sum, o);
        float inv = 1.f / (sum + 1e-9f);
        for (int base = start; base < end; base += 64) {
            int i = base + lane;
            if (i < end) alphaS[i] *= inv;
        }
    }
}

// hW[rl, n, e] = sum_d h[n,d] * W[r0+rl, d, e]  (LDS-tiled fp32 GEMM)
#define HPAD 68
__global__ __launch_bounds__(256) void hw_gemm_kernel(
        const float* __restrict__ h, const float* __restrict__ W,
        float* __restrict__ hW, int N, int r0) {
    __shared__ float Wl[64 * 64];
    __shared__ float hl[64 * HPAD];
    int t = threadIdx.x;
    int nodeBase = blockIdx.x * 64;
    int r = r0 + blockIdx.y;

    {
        const float4* Wg = (const float4*)(W + (size_t)r * 4096);
        float4* Wl4 = (float4*)Wl;
#pragma unroll
        for (int i = 0; i < 4; i++) Wl4[t + i * 256] = Wg[t + i * 256];
    }
    {
        const float4* hg = (const float4*)h;
#pragma unroll
        for (int i = 0; i < 4; i++) {
            int idx = t + i * 256;
            int row = idx >> 4, col4 = idx & 15;
            int node = nodeBase + row;
            float4 v = (node < N) ? hg[(size_t)node * 16 + col4] : float4{0.f, 0.f, 0.f, 0.f};
            float* p = &hl[row * HPAD + col4 * 4];
            p[0] = v.x; p[1] = v.y; p[2] = v.z; p[3] = v.w;
        }
    }
    __syncthreads();

    int e4 = (t & 15) * 4;
    int n4 = (t >> 4) * 4;
    float acc[4][4] = {};
    for (int d = 0; d < 64; d += 4) {
        float4 wv[4], hv[4];
#pragma unroll
        for (int dd = 0; dd < 4; dd++) wv[dd] = *(const float4*)&Wl[(d + dd) * 64 + e4];
#pragma unroll
        for (int i = 0; i < 4; i++) hv[i] = *(const float4*)&hl[(n4 + i) * HPAD + d];
#pragma unroll
        for (int i = 0; i < 4; i++) {
            const float hvv[4] = {hv[i].x, hv[i].y, hv[i].z, hv[i].w};
#pragma unroll
            for (int dd = 0; dd < 4; dd++) {
                const float* wp = (const float*)&wv[dd];
#pragma unroll
                for (int j = 0; j < 4; j++) acc[i][j] = fmaf(hvv[dd], wp[j], acc[i][j]);
            }
        }
    }
    size_t rowBase = (size_t)blockIdx.y * N;
#pragma unroll
    for (int i = 0; i < 4; i++) {
        int node = nodeBase + n4 + i;
        if (node < N) {
            float4 v = {acc[i][0], acc[i][1], acc[i][2], acc[i][3]};
            *(float4*)&hW[(rowBase + node) * 64 + e4] = v;
        }
    }
}

// dst-centric aggregation: one wave per dst, no atomics. ELU fused on last chunk.
__global__ __launch_bounds__(256) void agg_kernel(
        const int* __restrict__ rowptr, const int* __restrict__ perm,
        const int* __restrict__ src, const int* __restrict__ rel,
        const float* __restrict__ alphaS, const float* __restrict__ hW,
        float* __restrict__ agg, int n, int N, int r0, int r1, int last) {
    int g = blockIdx.x * blockDim.x + threadIdx.x;
    int wv = g >> 6, lane = g & 63;
    if (wv >= n) return;
    int start = rowptr[wv], end = rowptr[wv + 1];
    float acc = (r0 == 0) ? 0.f : agg[(size_t)wv * 64 + lane];

    // lane-parallel metadata load for first 64 edges, broadcast via shfl
    int i0 = start + lane;
    int rL = -1, sL = 0; float aL = 0.f;
    if (i0 < end) {
        int e = perm[i0];
        rL = rel[e]; sL = src[e]; aL = alphaS[i0];
    }
    int cnt = min(end - start, 64);
    for (int k = 0; k < cnt; k++) {
        int r = __shfl(rL, k); int s = __shfl(sL, k); float a = __shfl(aL, k);
        if (r >= r0 && r < r1)
            acc = fmaf(a, hW[((size_t)(r - r0) * N + s) * 64 + lane], acc);
    }
    for (int i = start + 64; i < end; i++) {
        int e = perm[i]; int r = rel[e];
        if (r >= r0 && r < r1)
            acc = fmaf(alphaS[i], hW[((size_t)(r - r0) * N + src[e]) * 64 + lane], acc);
    }
    if (last) acc = acc > 0.f ? acc : expm1f(acc);
    agg[(size_t)wv * 64 + lane] = acc;
}

// ================= pooling / readout / MLP =================
__global__ void seg_sum64_kernel(const float* __restrict__ h, const int* __restrict__ seg,
                                 float* __restrict__ out, int N) {
    int i = blockIdx.x * blockDim.x + threadIdx.x;
    if (i >= N * 64) return;
    int n = i >> 6, d = i & 63;
    atomAddF(&out[seg[n] * 64 + d], h[i]);
}

__global__ void readout_kernel(const float* __restrict__ molr, const float* __restrict__ mol,
                               const int* __restrict__ mol2rxn, float* __restrict__ feat, int M) {
    int i = blockIdx.x * blockDim.x + threadIdx.x;
    if (i >= M * 64) return;
    int m = i >> 6, d = i & 63;
    int b = mol2rxn[m];
    atomAddF(&feat[b * 128 + d], molr[i]);
    atomAddF(&feat[b * 128 + 64 + d], mol[i]);
}

// 16-batch-tiled: grid (2, 64), block 256
__global__ __launch_bounds__(256) void fc1_kernel(
        const float* __restrict__ feat, const float* __restrict__ w,
        const float* __restrict__ bias, const float* __restrict__ prelu,
        float* __restrict__ hm) {
    __shared__ float f[16 * 128];
    int t = threadIdx.x;
    int col = blockIdx.x * 256 + t;
    int b0 = blockIdx.y * 16;
    for (int i = t; i < 16 * 128; i += 256) f[i] = feat[(size_t)b0 * 128 + i];
    __syncthreads();
    float p = *prelu;
    float acc[16];
    float bv = bias[col];
#pragma unroll
    for (int b = 0; b < 16; b++) acc[b] = bv;
    for (int k = 0; k < 128; k++) {
        float wv = w[k * 512 + col];
#pragma unroll
        for (int b = 0; b < 16; b++) acc[b] = fmaf(f[b * 128 + k], wv, acc[b]);
    }
#pragma unroll
    for (int b = 0; b < 16; b++) {
        float v = acc[b];
        hm[(size_t)(b0 + b) * 512 + col] = v > 0.f ? v : p * v;
    }
}

// 16-batch-tiled: grid (3, 64), block 256
__global__ __launch_bounds__(256) void fc2_kernel(
        const float* __restrict__ hm, const float* __restrict__ w,
        const float* __restrict__ bias, float* __restrict__ out) {
    __shared__ float f[16 * 512];
    int t = threadIdx.x;
    int col = blockIdx.x * 256 + t;
    int b0 = blockIdx.y * 16;
    for (int i = t; i < 16 * 512; i += 256) f[i] = hm[(size_t)b0 * 512 + i];
    __syncthreads();
    if (col >= 703) return;
    float acc[16];
    float bv = bias[col];
#pragma unroll
    for (int b = 0; b < 16; b++) acc[b] = bv;
    for (int k = 0; k < 512; k++) {
        float wv = w[k * 703 + col];
#pragma unroll
        for (int b = 0; b < 16; b++) acc[b] = fmaf(f[b * 512 + k], wv, acc[b]);
    }
#pragma unroll
    for (int b = 0; b < 16; b++) out[(size_t)(b0 + b) * 703 + col] = acc[b];
}

// ================= launch =================
extern "C" void kernel_launch(void* const* d_in, const int* in_sizes, int n_in,
                              void* d_out, int out_size, void* d_ws, size_t ws_size,
                              hipStream_t stream) {
    const float* node_feats = (const float*)d_in[0];
    const int*   edge_src   = (const int*)d_in[1];
    const int*   edge_dst   = (const int*)d_in[2];
    const int*   edge_rel   = (const int*)d_in[3];
    const int*   node2mol   = (const int*)d_in[4];
    const int*   rxn_src    = (const int*)d_in[5];
    const int*   rxn_dst    = (const int*)d_in[6];
    const int*   rxn_rel    = (const int*)d_in[7];
    const int*   mol2rxn    = (const int*)d_in[8];
    const float* W1     = (const float*)d_in[9];
    const float* a_src1 = (const float*)d_in[10];
    const float* a_dst1 = (const float*)d_in[11];
    const float* W2     = (const float*)d_in[12];
    const float* a_src2 = (const float*)d_in[13];
    const float* a_dst2 = (const float*)d_in[14];
    const float* Wr     = (const float*)d_in[15];
    const float* a_srcr = (const float*)d_in[16];
    const float* a_dstr = (const float*)d_in[17];
    const float* w_fc1  = (const float*)d_in[18];
    const float* b_fc1  = (const float*)d_in[19];
    const float* prelu1 = (const float*)d_in[20];
    const float* w_fc2  = (const float*)d_in[21];
    const float* b_fc2  = (const float*)d_in[22];

    const int N = 100000, E = 800000, M = 5000, ER = 40000;

    float* ws = (float*)d_ws;
    float* h1     = ws;                       // 6,400,000
    float* h2     = h1 + 6400000;             // 6,400,000
    float* attS   = h2 + 6400000;             // 800,000
    float* attD   = attS + 800000;            // 800,000
    float* alphaS = attD + 800000;            // 800,000
    float* mol    = alphaS + 800000;          // 320,000
    float* molr   = mol + 320000;             // 320,000
    float* feat   = molr + 320000;            // 131,072
    float* hm     = feat + 131072;            // 524,288
    float* Vsrc   = hm + 524288;              // 512
    float* Vdst   = Vsrc + 512;               // 512
    int* rowptr   = (int*)(Vdst + 512);       // 100,008 (incl. pad)
    int* cnt      = rowptr + 100008;          // 100,000
    int* incl     = cnt + 100000;             // 100,000
    int* bsum     = incl + 100000;            // 512
    int* cursor   = bsum + 512;               // 100,000
    int* perm     = cursor + 100000;          // 800,000
    float* hWbuf  = (float*)(perm + 800000);  // rest: up to 8*N*64

    size_t usedFloats = (size_t)(hWbuf - ws);
    size_t availFloats = (ws_size / 4 > usedFloats) ? (ws_size / 4 - usedFloats) : 0;

    auto buildCSR = [&](const int* dstArr, int n, int e) {
        hipMemsetAsync(cnt, 0, (size_t)n * sizeof(int), stream);
        hist_kernel<<<dim3((e + 255) / 256), 256, 0, stream>>>(dstArr, cnt, e);
        int nb = (n + 255) / 256;
        scan1_kernel<<<dim3(nb), 256, 0, stream>>>(cnt, incl, bsum, n);
        scan2_kernel<<<dim3(1), 512, 0, stream>>>(bsum, nb);
        scan3_kernel<<<dim3((n + 256) / 256), 256, 0, stream>>>(incl, cnt, bsum, rowptr, cursor, n, e);
        scatter_kernel<<<dim3((e + 255) / 256), 256, 0, stream>>>(dstArr, cursor, perm, e);
    };

    auto rgat = [&](const float* hin, int n, int e, const int* es, const int* er,
                    const float* W, const float* as, const float* ad,
                    float* agg, int R) {
        compute_v_kernel<<<dim3((R * 64 + 63) / 64), 64, 0, stream>>>(W, as, ad, Vsrc, Vdst, R);
        node_att_kernel<<<dim3(((size_t)n * 64 + 255) / 256), 256, 0, stream>>>(hin, Vsrc, Vdst, attS, attD, n, R);
        alpha_kernel<<<dim3(((size_t)n * 64 + 255) / 256), 256, 0, stream>>>(
            rowptr, perm, es, er, attS, attD, alphaS, n, R);

        size_t perRel = (size_t)n * 64;
        int chunk = (int)(availFloats / perRel);
        if (chunk < 1) chunk = 1;
        if (chunk > R) chunk = R;
        for (int r0 = 0; r0 < R; r0 += chunk) {
            int r1 = r0 + chunk; if (r1 > R) r1 = R;
            hw_gemm_kernel<<<dim3((n + 63) / 64, r1 - r0), 256, 0, stream>>>(hin, W, hWbuf, n, r0);
            agg_kernel<<<dim3(((size_t)n * 64 + 255) / 256), 256, 0, stream>>>(
                rowptr, perm, es, er, alphaS, hWbuf, agg, n, N > n ? n : n, r0, r1, r1 == R ? 1 : 0);
        }
    };

    // ---- atom graph CSR (shared by both atom layers) ----
    buildCSR(edge_dst, N, E);
    rgat(node_feats, N, E, edge_src, edge_rel, W1, a_src1, a_dst1, h1, 8);
    rgat(h1,         N, E, edge_src, edge_rel, W2, a_src2, a_dst2, h2, 8);

    // ---- molecule pooling ----
    hipMemsetAsync(mol, 0, (size_t)M * 64 * sizeof(float), stream);
    seg_sum64_kernel<<<dim3(((size_t)N * 64 + 255) / 256), 256, 0, stream>>>(h2, node2mol, mol, N);

    // ---- reaction-graph RGAT (rebuild CSR for rxn graph) ----
    buildCSR(rxn_dst, M, ER);
    rgat(mol, M, ER, rxn_src, rxn_rel, Wr, a_srcr, a_dstr, molr, 4);

    // ---- reaction readout ----
    hipMemsetAsync(feat, 0, (size_t)1024 * 128 * sizeof(float), stream);
    readout_kernel<<<dim3(((size_t)M * 64 + 255) / 256), 256, 0, stream>>>(molr, mol, mol2rxn, feat, M);

    // ---- MLP head ----
    fc1_kernel<<<dim3(2, 64), 256, 0, stream>>>(feat, w_fc1, b_fc1, prelu1, hm);
    fc2_kernel<<<dim3(3, 64), 256, 0, stream>>>(hm, w_fc2, b_fc2, (float*)d_out);
}

// Round 5
// 1044.234 us; speedup vs baseline: 3.5924x; 1.1721x over previous
//
#include <hip/hip_runtime.h>
#include <math.h>

#define NEG_SLOPE 0.2f

__device__ __forceinline__ void atomAddF(float* p, float v) {
    unsafeAtomicAdd(p, v);   // HW global_atomic_add_f32 on gfx950
}

// ================= CSR build (counting sort by dst) =================
__global__ void hist_kernel(const int* __restrict__ dst, int* __restrict__ cnt, int E) {
    int e = blockIdx.x * blockDim.x + threadIdx.x;
    if (e < E) atomicAdd(&cnt[dst[e]], 1);
}

__global__ void scan1_kernel(const int* __restrict__ cnt, int* __restrict__ incl,
                             int* __restrict__ bsum, int n) {
    __shared__ int s[256];
    int t = threadIdx.x, i = blockIdx.x * 256 + t;
    int v = (i < n) ? cnt[i] : 0;
    s[t] = v; __syncthreads();
    for (int o = 1; o < 256; o <<= 1) {
        int u = (t >= o) ? s[t - o] : 0;
        __syncthreads(); s[t] += u; __syncthreads();
    }
    if (i < n) incl[i] = s[t];
    if (t == 255) bsum[blockIdx.x] = s[255];
}

__global__ void scan2_kernel(int* __restrict__ bsum, int nb) {
    __shared__ int s[512];
    int t = threadIdx.x;
    int v = (t < nb) ? bsum[t] : 0;
    s[t] = v; __syncthreads();
    for (int o = 1; o < 512; o <<= 1) {
        int u = (t >= o) ? s[t - o] : 0;
        __syncthreads(); s[t] += u; __syncthreads();
    }
    if (t < nb) bsum[t] = s[t] - v;   // exclusive
}

__global__ void scan3_kernel(const int* __restrict__ incl, const int* __restrict__ cnt,
                             const int* __restrict__ bsum, int* __restrict__ rowptr,
                             int* __restrict__ cursor, int n, int E) {
    int i = blockIdx.x * blockDim.x + threadIdx.x;
    if (i < n) {
        int v = incl[i] - cnt[i] + bsum[i >> 8];
        rowptr[i] = v; cursor[i] = v;
    } else if (i == n) {
        rowptr[n] = E;
    }
}

__global__ void scatter_kernel(const int* __restrict__ dst, int* __restrict__ cursor,
                               int* __restrict__ perm, int E) {
    int e = blockIdx.x * blockDim.x + threadIdx.x;
    if (e < E) { int pos = atomicAdd(&cursor[dst[e]], 1); perm[pos] = e; }
}

// ================= RGAT =================
__global__ void compute_v_kernel(const float* __restrict__ W,
                                 const float* __restrict__ a_src,
                                 const float* __restrict__ a_dst,
                                 float* __restrict__ Vsrc, float* __restrict__ Vdst,
                                 int R) {
    int idx = blockIdx.x * blockDim.x + threadIdx.x;   // r*64+d
    if (idx >= R * 64) return;
    int r = idx >> 6;
    const float* Wr = W + idx * 64;
    const float* as = a_src + r * 64;
    const float* ad = a_dst + r * 64;
    float s = 0.f, t = 0.f;
    for (int e = 0; e < 64; e++) { float w = Wr[e]; s = fmaf(w, as[e], s); t = fmaf(w, ad[e], t); }
    Vsrc[idx] = s; Vdst[idx] = t;
}

__global__ void node_att_kernel(const float* __restrict__ h,
                                const float* __restrict__ Vsrc,
                                const float* __restrict__ Vdst,
                                float* __restrict__ attS, float* __restrict__ attD,
                                int N, int R) {
    int wave = (blockIdx.x * blockDim.x + threadIdx.x) >> 6;
    int lane = threadIdx.x & 63;
    if (wave >= N) return;
    float x = h[(size_t)wave * 64 + lane];
    for (int r = 0; r < R; r++) {
        float s = x * Vsrc[r * 64 + lane];
        float t = x * Vdst[r * 64 + lane];
        for (int o = 32; o; o >>= 1) { s += __shfl_xor(s, o); t += __shfl_xor(t, o); }
        if (lane == 0) { attS[wave * R + r] = s; attD[wave * R + r] = t; }
    }
}

__global__ __launch_bounds__(256) void alpha_kernel(
        const int* __restrict__ rowptr, const int* __restrict__ perm,
        const int* __restrict__ src, const int* __restrict__ rel,
        const float* __restrict__ attS, const float* __restrict__ attD,
        float* __restrict__ alphaS, int n, int R) {
    int g = blockIdx.x * blockDim.x + threadIdx.x;
    int wv = g >> 6, lane = g & 63;
    if (wv >= n) return;
    int start = rowptr[wv], end = rowptr[wv + 1];
    int deg = end - start;
    if (deg <= 0) return;
    if (deg <= 64) {
        int i = start + lane;
        bool act = i < end;
        float s = -INFINITY;
        if (act) {
            int e = perm[i]; int r = rel[e];
            float sc = attS[src[e] * R + r] + attD[wv * R + r];
            s = sc > 0.f ? sc : NEG_SLOPE * sc;
        }
        float m = s;
        for (int o = 32; o; o >>= 1) m = fmaxf(m, __shfl_xor(m, o));
        float ex = act ? expf(s - m) : 0.f;
        float sum = ex;
        for (int o = 32; o; o >>= 1) sum += __shfl_xor(sum, o);
        float inv = 1.f / (sum + 1e-9f);
        if (act) alphaS[i] = ex * inv;
    } else {
        float m = -INFINITY;
        for (int base = start; base < end; base += 64) {
            int i = base + lane;
            if (i < end) {
                int e = perm[i]; int r = rel[e];
                float sc = attS[src[e] * R + r] + attD[wv * R + r];
                sc = sc > 0.f ? sc : NEG_SLOPE * sc;
                alphaS[i] = sc;
                m = fmaxf(m, sc);
            }
        }
        for (int o = 32; o; o >>= 1) m = fmaxf(m, __shfl_xor(m, o));
        float sum = 0.f;
        for (int base = start; base < end; base += 64) {
            int i = base + lane;
            if (i < end) { float ex = expf(alphaS[i] - m); alphaS[i] = ex; sum += ex; }
        }
        for (int o = 32; o; o >>= 1) sum += __shfl_xor(sum, o);
        float inv = 1.f / (sum + 1e-9f);
        for (int base = start; base < end; base += 64) {
            int i = base + lane;
            if (i < end) alphaS[i] *= inv;
        }
    }
}

// hW[rl, n, e] = sum_d h[n,d] * W[r0+rl, d, e]  (LDS-tiled fp32 GEMM)
#define HPAD 68
__global__ __launch_bounds__(256) void hw_gemm_kernel(
        const float* __restrict__ h, const float* __restrict__ W,
        float* __restrict__ hW, int N, int r0) {
    __shared__ float Wl[64 * 64];
    __shared__ float hl[64 * HPAD];
    int t = threadIdx.x;
    int nodeBase = blockIdx.x * 64;
    int r = r0 + blockIdx.y;

    {
        const float4* Wg = (const float4*)(W + (size_t)r * 4096);
        float4* Wl4 = (float4*)Wl;
#pragma unroll
        for (int i = 0; i < 4; i++) Wl4[t + i * 256] = Wg[t + i * 256];
    }
    {
        const float4* hg = (const float4*)h;
#pragma unroll
        for (int i = 0; i < 4; i++) {
            int idx = t + i * 256;
            int row = idx >> 4, col4 = idx & 15;
            int node = nodeBase + row;
            float4 v = (node < N) ? hg[(size_t)node * 16 + col4] : float4{0.f, 0.f, 0.f, 0.f};
            float* p = &hl[row * HPAD + col4 * 4];
            p[0] = v.x; p[1] = v.y; p[2] = v.z; p[3] = v.w;
        }
    }
    __syncthreads();

    int e4 = (t & 15) * 4;
    int n4 = (t >> 4) * 4;
    float acc[4][4] = {};
    for (int d = 0; d < 64; d += 4) {
        float4 wv[4], hv[4];
#pragma unroll
        for (int dd = 0; dd < 4; dd++) wv[dd] = *(const float4*)&Wl[(d + dd) * 64 + e4];
#pragma unroll
        for (int i = 0; i < 4; i++) hv[i] = *(const float4*)&hl[(n4 + i) * HPAD + d];
#pragma unroll
        for (int i = 0; i < 4; i++) {
            const float hvv[4] = {hv[i].x, hv[i].y, hv[i].z, hv[i].w};
#pragma unroll
            for (int dd = 0; dd < 4; dd++) {
                const float* wp = (const float*)&wv[dd];
#pragma unroll
                for (int j = 0; j < 4; j++) acc[i][j] = fmaf(hvv[dd], wp[j], acc[i][j]);
            }
        }
    }
    size_t rowBase = (size_t)blockIdx.y * N;
#pragma unroll
    for (int i = 0; i < 4; i++) {
        int node = nodeBase + n4 + i;
        if (node < N) {
            float4 v = {acc[i][0], acc[i][1], acc[i][2], acc[i][3]};
            *(float4*)&hW[(rowBase + node) * 64 + e4] = v;
        }
    }
}

// dst-centric aggregation: one wave per dst, no atomics. ELU fused on last chunk.
__global__ __launch_bounds__(256) void agg_kernel(
        const int* __restrict__ rowptr, const int* __restrict__ perm,
        const int* __restrict__ src, const int* __restrict__ rel,
        const float* __restrict__ alphaS, const float* __restrict__ hW,
        float* __restrict__ agg, int n, int N, int r0, int r1, int last) {
    int g = blockIdx.x * blockDim.x + threadIdx.x;
    int wv = g >> 6, lane = g & 63;
    if (wv >= n) return;
    int start = rowptr[wv], end = rowptr[wv + 1];
    float acc = (r0 == 0) ? 0.f : agg[(size_t)wv * 64 + lane];

    int i0 = start + lane;
    int rL = -1, sL = 0; float aL = 0.f;
    if (i0 < end) {
        int e = perm[i0];
        rL = rel[e]; sL = src[e]; aL = alphaS[i0];
    }
    int cnt = min(end - start, 64);
    for (int k = 0; k < cnt; k++) {
        int r = __shfl(rL, k); int s = __shfl(sL, k); float a = __shfl(aL, k);
        if (r >= r0 && r < r1)
            acc = fmaf(a, hW[((size_t)(r - r0) * N + s) * 64 + lane], acc);
    }
    for (int i = start + 64; i < end; i++) {
        int e = perm[i]; int r = rel[e];
        if (r >= r0 && r < r1)
            acc = fmaf(alphaS[i], hW[((size_t)(r - r0) * N + src[e]) * 64 + lane], acc);
    }
    if (last) acc = acc > 0.f ? acc : expm1f(acc);
    agg[(size_t)wv * 64 + lane] = acc;
}

// ================= pooling / readout =================
__global__ void seg_sum64_kernel(const float* __restrict__ h, const int* __restrict__ seg,
                                 float* __restrict__ out, int N) {
    int i = blockIdx.x * blockDim.x + threadIdx.x;
    if (i >= N * 64) return;
    int n = i >> 6, d = i & 63;
    atomAddF(&out[seg[n] * 64 + d], h[i]);
}

__global__ void readout_kernel(const float* __restrict__ molr, const float* __restrict__ mol,
                               const int* __restrict__ mol2rxn, float* __restrict__ feat, int M) {
    int i = blockIdx.x * blockDim.x + threadIdx.x;
    if (i >= M * 64) return;
    int m = i >> 6, d = i & 63;
    int b = mol2rxn[m];
    atomAddF(&feat[b * 128 + d], molr[i]);
    atomAddF(&feat[b * 128 + 64 + d], mol[i]);
}

// ================= MLP head: LDS-tiled GEMM =================
// C[M,N] = act(A[M,K] @ B[K,N] + bias). 64x64 tile / 256 threads, 4x4 micro-tile.
// K must be a multiple of 32. mode=1 -> PReLU epilogue.
#define APAD 36
__global__ __launch_bounds__(256) void fc_gemm_kernel(
        const float* __restrict__ A, const float* __restrict__ B,
        const float* __restrict__ bias, const float* __restrict__ prelu,
        float* __restrict__ C, int M, int N, int K, int mode) {
    __shared__ float Al[64 * APAD];   // [row][k-chunk 32], padded
    __shared__ float Bl[32 * 64];     // [k][col]
    int t = threadIdx.x;
    int n0 = blockIdx.x * 64, m0 = blockIdx.y * 64;
    int e4 = (t & 15) * 4;
    int n4 = (t >> 4) * 4;
    float acc[4][4] = {};

    for (int k0 = 0; k0 < K; k0 += 32) {
        // stage A chunk: 64 rows x 32 k = 512 float4 (2/thread)
        {
            const float4* Ag = (const float4*)A;
#pragma unroll
            for (int i = 0; i < 2; i++) {
                int idx = t + i * 256;
                int row = idx >> 3, c4 = idx & 7;
                float4 v = Ag[(size_t)(m0 + row) * (K >> 2) + (k0 >> 2) + c4];
                float* p = &Al[row * APAD + c4 * 4];
                p[0] = v.x; p[1] = v.y; p[2] = v.z; p[3] = v.w;
            }
        }
        // stage B chunk: 32 k x 64 cols = 512 float4 (2/thread), col-guarded
        {
#pragma unroll
            for (int i = 0; i < 2; i++) {
                int idx = t + i * 256;
                int kk = idx >> 4, c4 = (idx & 15) * 4;
                int col = n0 + c4;
                float4 v;
                const float* Brow = B + (size_t)(k0 + kk) * N;
                if (col + 3 < N) v = *(const float4*)&Brow[col];
                else {
                    v.x = (col + 0 < N) ? Brow[col + 0] : 0.f;
                    v.y = (col + 1 < N) ? Brow[col + 1] : 0.f;
                    v.z = (col + 2 < N) ? Brow[col + 2] : 0.f;
                    v.w = 0.f;
                }
                *(float4*)&Bl[kk * 64 + c4] = v;
            }
        }
        __syncthreads();
        for (int d = 0; d < 32; d += 4) {
            float4 wv[4], hv[4];
#pragma unroll
            for (int dd = 0; dd < 4; dd++) wv[dd] = *(const float4*)&Bl[(d + dd) * 64 + e4];
#pragma unroll
            for (int i = 0; i < 4; i++) hv[i] = *(const float4*)&Al[(n4 + i) * APAD + d];
#pragma unroll
            for (int i = 0; i < 4; i++) {
                const float hvv[4] = {hv[i].x, hv[i].y, hv[i].z, hv[i].w};
#pragma unroll
                for (int dd = 0; dd < 4; dd++) {
                    const float* wp = (const float*)&wv[dd];
#pragma unroll
                    for (int j = 0; j < 4; j++) acc[i][j] = fmaf(hvv[dd], wp[j], acc[i][j]);
                }
            }
        }
        __syncthreads();
    }

    float p = mode ? *prelu : 0.f;
#pragma unroll
    for (int i = 0; i < 4; i++) {
        int row = m0 + n4 + i;
#pragma unroll
        for (int j = 0; j < 4; j++) {
            int col = n0 + e4 + j;
            if (col < N) {
                float v = acc[i][j] + bias[col];
                if (mode) v = v > 0.f ? v : p * v;
                C[(size_t)row * N + col] = v;
            }
        }
    }
}

// ================= launch =================
extern "C" void kernel_launch(void* const* d_in, const int* in_sizes, int n_in,
                              void* d_out, int out_size, void* d_ws, size_t ws_size,
                              hipStream_t stream) {
    const float* node_feats = (const float*)d_in[0];
    const int*   edge_src   = (const int*)d_in[1];
    const int*   edge_dst   = (const int*)d_in[2];
    const int*   edge_rel   = (const int*)d_in[3];
    const int*   node2mol   = (const int*)d_in[4];
    const int*   rxn_src    = (const int*)d_in[5];
    const int*   rxn_dst    = (const int*)d_in[6];
    const int*   rxn_rel    = (const int*)d_in[7];
    const int*   mol2rxn    = (const int*)d_in[8];
    const float* W1     = (const float*)d_in[9];
    const float* a_src1 = (const float*)d_in[10];
    const float* a_dst1 = (const float*)d_in[11];
    const float* W2     = (const float*)d_in[12];
    const float* a_src2 = (const float*)d_in[13];
    const float* a_dst2 = (const float*)d_in[14];
    const float* Wr     = (const float*)d_in[15];
    const float* a_srcr = (const float*)d_in[16];
    const float* a_dstr = (const float*)d_in[17];
    const float* w_fc1  = (const float*)d_in[18];
    const float* b_fc1  = (const float*)d_in[19];
    const float* prelu1 = (const float*)d_in[20];
    const float* w_fc2  = (const float*)d_in[21];
    const float* b_fc2  = (const float*)d_in[22];

    const int N = 100000, E = 800000, M = 5000, ER = 40000;

    float* ws = (float*)d_ws;
    float* h1     = ws;                       // 6,400,000
    float* h2     = h1 + 6400000;             // 6,400,000
    float* attS   = h2 + 6400000;             // 800,000
    float* attD   = attS + 800000;            // 800,000
    float* alphaS = attD + 800000;            // 800,000
    float* mol    = alphaS + 800000;          // 320,000
    float* molr   = mol + 320000;             // 320,000
    float* feat   = molr + 320000;            // 131,072
    float* hm     = feat + 131072;            // 524,288
    float* Vsrc   = hm + 524288;              // 512
    float* Vdst   = Vsrc + 512;               // 512
    int* rowptr   = (int*)(Vdst + 512);       // 100,008
    int* cnt      = rowptr + 100008;          // 100,000
    int* incl     = cnt + 100000;             // 100,000
    int* bsum     = incl + 100000;            // 512
    int* cursor   = bsum + 512;               // 100,000
    int* perm     = cursor + 100000;          // 800,000
    float* hWbuf  = (float*)(perm + 800000);  // rest: up to 8*N*64

    size_t usedFloats = (size_t)(hWbuf - ws);
    size_t availFloats = (ws_size / 4 > usedFloats) ? (ws_size / 4 - usedFloats) : 0;

    auto buildCSR = [&](const int* dstArr, int n, int e) {
        hipMemsetAsync(cnt, 0, (size_t)n * sizeof(int), stream);
        hist_kernel<<<dim3((e + 255) / 256), 256, 0, stream>>>(dstArr, cnt, e);
        int nb = (n + 255) / 256;
        scan1_kernel<<<dim3(nb), 256, 0, stream>>>(cnt, incl, bsum, n);
        scan2_kernel<<<dim3(1), 512, 0, stream>>>(bsum, nb);
        scan3_kernel<<<dim3((n + 256) / 256), 256, 0, stream>>>(incl, cnt, bsum, rowptr, cursor, n, e);
        scatter_kernel<<<dim3((e + 255) / 256), 256, 0, stream>>>(dstArr, cursor, perm, e);
    };

    auto rgat = [&](const float* hin, int n, int e, const int* es, const int* er,
                    const float* W, const float* as, const float* ad,
                    float* agg, int R) {
        compute_v_kernel<<<dim3((R * 64 + 63) / 64), 64, 0, stream>>>(W, as, ad, Vsrc, Vdst, R);
        node_att_kernel<<<dim3(((size_t)n * 64 + 255) / 256), 256, 0, stream>>>(hin, Vsrc, Vdst, attS, attD, n, R);
        alpha_kernel<<<dim3(((size_t)n * 64 + 255) / 256), 256, 0, stream>>>(
            rowptr, perm, es, er, attS, attD, alphaS, n, R);

        size_t perRel = (size_t)n * 64;
        int chunk = (int)(availFloats / perRel);
        if (chunk < 1) chunk = 1;
        if (chunk > R) chunk = R;
        for (int r0 = 0; r0 < R; r0 += chunk) {
            int r1 = r0 + chunk; if (r1 > R) r1 = R;
            hw_gemm_kernel<<<dim3((n + 63) / 64, r1 - r0), 256, 0, stream>>>(hin, W, hWbuf, n, r0);
            agg_kernel<<<dim3(((size_t)n * 64 + 255) / 256), 256, 0, stream>>>(
                rowptr, perm, es, er, alphaS, hWbuf, agg, n, n, r0, r1, r1 == R ? 1 : 0);
        }
    };

    // ---- atom graph CSR (shared by both atom layers) ----
    buildCSR(edge_dst, N, E);
    rgat(node_feats, N, E, edge_src, edge_rel, W1, a_src1, a_dst1, h1, 8);
    rgat(h1,         N, E, edge_src, edge_rel, W2, a_src2, a_dst2, h2, 8);

    // ---- molecule pooling ----
    hipMemsetAsync(mol, 0, (size_t)M * 64 * sizeof(float), stream);
    seg_sum64_kernel<<<dim3(((size_t)N * 64 + 255) / 256), 256, 0, stream>>>(h2, node2mol, mol, N);

    // ---- reaction-graph RGAT ----
    buildCSR(rxn_dst, M, ER);
    rgat(mol, M, ER, rxn_src, rxn_rel, Wr, a_srcr, a_dstr, molr, 4);

    // ---- reaction readout ----
    hipMemsetAsync(feat, 0, (size_t)1024 * 128 * sizeof(float), stream);
    readout_kernel<<<dim3(((size_t)M * 64 + 255) / 256), 256, 0, stream>>>(molr, mol, mol2rxn, feat, M);

    // ---- MLP head: tiled GEMMs ----
    fc_gemm_kernel<<<dim3(8, 16), 256, 0, stream>>>(feat, w_fc1, b_fc1, prelu1, hm, 1024, 512, 128, 1);
    fc_gemm_kernel<<<dim3(11, 16), 256, 0, stream>>>(hm, w_fc2, b_fc2, nullptr, (float*)d_out, 1024, 703, 512, 0);
}

// Round 6
// 868.044 us; speedup vs baseline: 4.3216x; 1.2030x over previous
//
#include <hip/hip_runtime.h>
#include <math.h>

#define NEG_SLOPE 0.2f

__device__ __forceinline__ void atomAddF(float* p, float v) {
    unsafeAtomicAdd(p, v);   // HW global_atomic_add_f32 on gfx950
}

// ================= CSR build (counting sort by dst) =================
__global__ void hist_kernel(const int* __restrict__ dst, int* __restrict__ cnt, int E) {
    int e = blockIdx.x * blockDim.x + threadIdx.x;
    if (e < E) atomicAdd(&cnt[dst[e]], 1);
}

__global__ void scan1_kernel(const int* __restrict__ cnt, int* __restrict__ incl,
                             int* __restrict__ bsum, int n) {
    __shared__ int s[256];
    int t = threadIdx.x, i = blockIdx.x * 256 + t;
    int v = (i < n) ? cnt[i] : 0;
    s[t] = v; __syncthreads();
    for (int o = 1; o < 256; o <<= 1) {
        int u = (t >= o) ? s[t - o] : 0;
        __syncthreads(); s[t] += u; __syncthreads();
    }
    if (i < n) incl[i] = s[t];
    if (t == 255) bsum[blockIdx.x] = s[255];
}

__global__ void scan2_kernel(int* __restrict__ bsum, int nb) {
    __shared__ int s[512];
    int t = threadIdx.x;
    int v = (t < nb) ? bsum[t] : 0;
    s[t] = v; __syncthreads();
    for (int o = 1; o < 512; o <<= 1) {
        int u = (t >= o) ? s[t - o] : 0;
        __syncthreads(); s[t] += u; __syncthreads();
    }
    if (t < nb) bsum[t] = s[t] - v;   // exclusive
}

__global__ void scan3_kernel(const int* __restrict__ incl, const int* __restrict__ cnt,
                             const int* __restrict__ bsum, int* __restrict__ rowptr,
                             int* __restrict__ cursor, int n, int E) {
    int i = blockIdx.x * blockDim.x + threadIdx.x;
    if (i < n) {
        int v = incl[i] - cnt[i] + bsum[i >> 8];
        rowptr[i] = v; cursor[i] = v;
    } else if (i == n) {
        rowptr[n] = E;
    }
}

__global__ void scatter_kernel(const int* __restrict__ dst, int* __restrict__ cursor,
                               int* __restrict__ perm, int E) {
    int e = blockIdx.x * blockDim.x + threadIdx.x;
    if (e < E) { int pos = atomicAdd(&cursor[dst[e]], 1); perm[pos] = e; }
}

// ================= RGAT =================
__global__ void compute_v_kernel(const float* __restrict__ W,
                                 const float* __restrict__ a_src,
                                 const float* __restrict__ a_dst,
                                 float* __restrict__ Vsrc, float* __restrict__ Vdst,
                                 int R) {
    int idx = blockIdx.x * blockDim.x + threadIdx.x;   // r*64+d
    if (idx >= R * 64) return;
    int r = idx >> 6;
    const float* Wr = W + idx * 64;
    const float* as = a_src + r * 64;
    const float* ad = a_dst + r * 64;
    float s = 0.f, t = 0.f;
    for (int e = 0; e < 64; e++) { float w = Wr[e]; s = fmaf(w, as[e], s); t = fmaf(w, ad[e], t); }
    Vsrc[idx] = s; Vdst[idx] = t;
}

// attS[n*R+r] = h[n,:] . Vsrc[r,:]  -- skinny GEMM, 64-node LDS tile.
#define HPAD 68
__global__ __launch_bounds__(256) void att_gemm_kernel(
        const float* __restrict__ h,
        const float* __restrict__ Vsrc, const float* __restrict__ Vdst,
        float* __restrict__ attS, float* __restrict__ attD,
        int N, int R) {
    __shared__ float hl[64 * HPAD];
    __shared__ float Vs[8 * HPAD];
    __shared__ float Vd[8 * HPAD];
    int t = threadIdx.x;
    int n0 = blockIdx.x * 64;

    // stage h tile (64 rows x 16 float4)
    {
        const float4* hg = (const float4*)h;
#pragma unroll
        for (int i = 0; i < 4; i++) {
            int idx = t + i * 256;
            int row = idx >> 4, col4 = idx & 15;
            int node = n0 + row;
            float4 v = (node < N) ? hg[(size_t)node * 16 + col4] : float4{0.f, 0.f, 0.f, 0.f};
            *(float4*)&hl[row * HPAD + col4 * 4] = v;
        }
    }
    // stage Vsrc/Vdst padded (R<=8)
    for (int i = t; i < R * 64; i += 256) {
        int r = i >> 6, d = i & 63;
        Vs[r * HPAD + d] = Vsrc[i];
        Vd[r * HPAD + d] = Vdst[i];
    }
    __syncthreads();

    for (int p = t; p < 64 * R; p += 256) {
        int node = p / R, r = p - node * R;
        const float4* hp = (const float4*)&hl[node * HPAD];
        const float4* sp = (const float4*)&Vs[r * HPAD];
        const float4* dp = (const float4*)&Vd[r * HPAD];
        float s = 0.f, dd = 0.f;
#pragma unroll
        for (int d4 = 0; d4 < 16; d4++) {
            float4 hv = hp[d4], sv = sp[d4], dv = dp[d4];
            s  = fmaf(hv.x, sv.x, s);  s  = fmaf(hv.y, sv.y, s);
            s  = fmaf(hv.z, sv.z, s);  s  = fmaf(hv.w, sv.w, s);
            dd = fmaf(hv.x, dv.x, dd); dd = fmaf(hv.y, dv.y, dd);
            dd = fmaf(hv.z, dv.z, dd); dd = fmaf(hv.w, dv.w, dd);
        }
        int gn = n0 + node;
        if (gn < N) { attS[(size_t)gn * R + r] = s; attD[(size_t)gn * R + r] = dd; }
    }
}

__global__ __launch_bounds__(256) void alpha_kernel(
        const int* __restrict__ rowptr, const int* __restrict__ perm,
        const int* __restrict__ src, const int* __restrict__ rel,
        const float* __restrict__ attS, const float* __restrict__ attD,
        float* __restrict__ alphaS, int n, int R) {
    int g = blockIdx.x * blockDim.x + threadIdx.x;
    int wv = g >> 6, lane = g & 63;
    if (wv >= n) return;
    int start = rowptr[wv], end = rowptr[wv + 1];
    int deg = end - start;
    if (deg <= 0) return;
    if (deg <= 64) {
        int i = start + lane;
        bool act = i < end;
        float s = -INFINITY;
        if (act) {
            int e = perm[i]; int r = rel[e];
            float sc = attS[src[e] * R + r] + attD[wv * R + r];
            s = sc > 0.f ? sc : NEG_SLOPE * sc;
        }
        float m = s;
        for (int o = 32; o; o >>= 1) m = fmaxf(m, __shfl_xor(m, o));
        float ex = act ? expf(s - m) : 0.f;
        float sum = ex;
        for (int o = 32; o; o >>= 1) sum += __shfl_xor(sum, o);
        float inv = 1.f / (sum + 1e-9f);
        if (act) alphaS[i] = ex * inv;
    } else {
        float m = -INFINITY;
        for (int base = start; base < end; base += 64) {
            int i = base + lane;
            if (i < end) {
                int e = perm[i]; int r = rel[e];
                float sc = attS[src[e] * R + r] + attD[wv * R + r];
                sc = sc > 0.f ? sc : NEG_SLOPE * sc;
                alphaS[i] = sc;
                m = fmaxf(m, sc);
            }
        }
        for (int o = 32; o; o >>= 1) m = fmaxf(m, __shfl_xor(m, o));
        float sum = 0.f;
        for (int base = start; base < end; base += 64) {
            int i = base + lane;
            if (i < end) { float ex = expf(alphaS[i] - m); alphaS[i] = ex; sum += ex; }
        }
        for (int o = 32; o; o >>= 1) sum += __shfl_xor(sum, o);
        float inv = 1.f / (sum + 1e-9f);
        for (int base = start; base < end; base += 64) {
            int i = base + lane;
            if (i < end) alphaS[i] *= inv;
        }
    }
}

// hW[rl, n, e] = sum_d h[n,d] * W[r0+rl, d, e]  (LDS-tiled fp32 GEMM)
__global__ __launch_bounds__(256) void hw_gemm_kernel(
        const float* __restrict__ h, const float* __restrict__ W,
        float* __restrict__ hW, int N, int r0) {
    __shared__ float Wl[64 * 64];
    __shared__ float hl[64 * HPAD];
    int t = threadIdx.x;
    int nodeBase = blockIdx.x * 64;
    int r = r0 + blockIdx.y;

    {
        const float4* Wg = (const float4*)(W + (size_t)r * 4096);
        float4* Wl4 = (float4*)Wl;
#pragma unroll
        for (int i = 0; i < 4; i++) Wl4[t + i * 256] = Wg[t + i * 256];
    }
    {
        const float4* hg = (const float4*)h;
#pragma unroll
        for (int i = 0; i < 4; i++) {
            int idx = t + i * 256;
            int row = idx >> 4, col4 = idx & 15;
            int node = nodeBase + row;
            float4 v = (node < N) ? hg[(size_t)node * 16 + col4] : float4{0.f, 0.f, 0.f, 0.f};
            float* p = &hl[row * HPAD + col4 * 4];
            p[0] = v.x; p[1] = v.y; p[2] = v.z; p[3] = v.w;
        }
    }
    __syncthreads();

    int e4 = (t & 15) * 4;
    int n4 = (t >> 4) * 4;
    float acc[4][4] = {};
    for (int d = 0; d < 64; d += 4) {
        float4 wv[4], hv[4];
#pragma unroll
        for (int dd = 0; dd < 4; dd++) wv[dd] = *(const float4*)&Wl[(d + dd) * 64 + e4];
#pragma unroll
        for (int i = 0; i < 4; i++) hv[i] = *(const float4*)&hl[(n4 + i) * HPAD + d];
#pragma unroll
        for (int i = 0; i < 4; i++) {
            const float hvv[4] = {hv[i].x, hv[i].y, hv[i].z, hv[i].w};
#pragma unroll
            for (int dd = 0; dd < 4; dd++) {
                const float* wp = (const float*)&wv[dd];
#pragma unroll
                for (int j = 0; j < 4; j++) acc[i][j] = fmaf(hvv[dd], wp[j], acc[i][j]);
            }
        }
    }
    size_t rowBase = (size_t)blockIdx.y * N;
#pragma unroll
    for (int i = 0; i < 4; i++) {
        int node = nodeBase + n4 + i;
        if (node < N) {
            float4 v = {acc[i][0], acc[i][1], acc[i][2], acc[i][3]};
            *(float4*)&hW[(rowBase + node) * 64 + e4] = v;
        }
    }
}

// dst-centric aggregation: one wave per dst, no atomics. ELU fused on last chunk.
__global__ __launch_bounds__(256) void agg_kernel(
        const int* __restrict__ rowptr, const int* __restrict__ perm,
        const int* __restrict__ src, const int* __restrict__ rel,
        const float* __restrict__ alphaS, const float* __restrict__ hW,
        float* __restrict__ agg, int n, int N, int r0, int r1, int last) {
    int g = blockIdx.x * blockDim.x + threadIdx.x;
    int wv = g >> 6, lane = g & 63;
    if (wv >= n) return;
    int start = rowptr[wv], end = rowptr[wv + 1];
    float acc = (r0 == 0) ? 0.f : agg[(size_t)wv * 64 + lane];

    int i0 = start + lane;
    int rL = -1, sL = 0; float aL = 0.f;
    if (i0 < end) {
        int e = perm[i0];
        rL = rel[e]; sL = src[e]; aL = alphaS[i0];
    }
    int cnt = min(end - start, 64);
    for (int k = 0; k < cnt; k++) {
        int r = __shfl(rL, k); int s = __shfl(sL, k); float a = __shfl(aL, k);
        if (r >= r0 && r < r1)
            acc = fmaf(a, hW[((size_t)(r - r0) * N + s) * 64 + lane], acc);
    }
    for (int i = start + 64; i < end; i++) {
        int e = perm[i]; int r = rel[e];
        if (r >= r0 && r < r1)
            acc = fmaf(alphaS[i], hW[((size_t)(r - r0) * N + src[e]) * 64 + lane], acc);
    }
    if (last) acc = acc > 0.f ? acc : expm1f(acc);
    agg[(size_t)wv * 64 + lane] = acc;
}

// ================= pooling / readout =================
__global__ void seg_sum64_kernel(const float* __restrict__ h, const int* __restrict__ seg,
                                 float* __restrict__ out, int N) {
    int i = blockIdx.x * blockDim.x + threadIdx.x;
    if (i >= N * 64) return;
    int n = i >> 6, d = i & 63;
    atomAddF(&out[seg[n] * 64 + d], h[i]);
}

__global__ void readout_kernel(const float* __restrict__ molr, const float* __restrict__ mol,
                               const int* __restrict__ mol2rxn, float* __restrict__ feat, int M) {
    int i = blockIdx.x * blockDim.x + threadIdx.x;
    if (i >= M * 64) return;
    int m = i >> 6, d = i & 63;
    int b = mol2rxn[m];
    atomAddF(&feat[b * 128 + d], molr[i]);
    atomAddF(&feat[b * 128 + 64 + d], mol[i]);
}

// ================= MLP head: LDS-tiled GEMM =================
#define APAD 36
__global__ __launch_bounds__(256) void fc_gemm_kernel(
        const float* __restrict__ A, const float* __restrict__ B,
        const float* __restrict__ bias, const float* __restrict__ prelu,
        float* __restrict__ C, int M, int N, int K, int mode) {
    __shared__ float Al[64 * APAD];
    __shared__ float Bl[32 * 64];
    int t = threadIdx.x;
    int n0 = blockIdx.x * 64, m0 = blockIdx.y * 64;
    int e4 = (t & 15) * 4;
    int n4 = (t >> 4) * 4;
    float acc[4][4] = {};

    for (int k0 = 0; k0 < K; k0 += 32) {
        {
            const float4* Ag = (const float4*)A;
#pragma unroll
            for (int i = 0; i < 2; i++) {
                int idx = t + i * 256;
                int row = idx >> 3, c4 = idx & 7;
                float4 v = Ag[(size_t)(m0 + row) * (K >> 2) + (k0 >> 2) + c4];
                float* p = &Al[row * APAD + c4 * 4];
                p[0] = v.x; p[1] = v.y; p[2] = v.z; p[3] = v.w;
            }
        }
        {
#pragma unroll
            for (int i = 0; i < 2; i++) {
                int idx = t + i * 256;
                int kk = idx >> 4, c4 = (idx & 15) * 4;
                int col = n0 + c4;
                float4 v;
                const float* Brow = B + (size_t)(k0 + kk) * N;
                if (col + 3 < N) v = *(const float4*)&Brow[col];
                else {
                    v.x = (col + 0 < N) ? Brow[col + 0] : 0.f;
                    v.y = (col + 1 < N) ? Brow[col + 1] : 0.f;
                    v.z = (col + 2 < N) ? Brow[col + 2] : 0.f;
                    v.w = 0.f;
                }
                *(float4*)&Bl[kk * 64 + c4] = v;
            }
        }
        __syncthreads();
        for (int d = 0; d < 32; d += 4) {
            float4 wv[4], hv[4];
#pragma unroll
            for (int dd = 0; dd < 4; dd++) wv[dd] = *(const float4*)&Bl[(d + dd) * 64 + e4];
#pragma unroll
            for (int i = 0; i < 4; i++) hv[i] = *(const float4*)&Al[(n4 + i) * APAD + d];
#pragma unroll
            for (int i = 0; i < 4; i++) {
                const float hvv[4] = {hv[i].x, hv[i].y, hv[i].z, hv[i].w};
#pragma unroll
                for (int dd = 0; dd < 4; dd++) {
                    const float* wp = (const float*)&wv[dd];
#pragma unroll
                    for (int j = 0; j < 4; j++) acc[i][j] = fmaf(hvv[dd], wp[j], acc[i][j]);
                }
            }
        }
        __syncthreads();
    }

    float p = mode ? *prelu : 0.f;
#pragma unroll
    for (int i = 0; i < 4; i++) {
        int row = m0 + n4 + i;
#pragma unroll
        for (int j = 0; j < 4; j++) {
            int col = n0 + e4 + j;
            if (col < N) {
                float v = acc[i][j] + bias[col];
                if (mode) v = v > 0.f ? v : p * v;
                C[(size_t)row * N + col] = v;
            }
        }
    }
}

// ================= launch =================
extern "C" void kernel_launch(void* const* d_in, const int* in_sizes, int n_in,
                              void* d_out, int out_size, void* d_ws, size_t ws_size,
                              hipStream_t stream) {
    const float* node_feats = (const float*)d_in[0];
    const int*   edge_src   = (const int*)d_in[1];
    const int*   edge_dst   = (const int*)d_in[2];
    const int*   edge_rel   = (const int*)d_in[3];
    const int*   node2mol   = (const int*)d_in[4];
    const int*   rxn_src    = (const int*)d_in[5];
    const int*   rxn_dst    = (const int*)d_in[6];
    const int*   rxn_rel    = (const int*)d_in[7];
    const int*   mol2rxn    = (const int*)d_in[8];
    const float* W1     = (const float*)d_in[9];
    const float* a_src1 = (const float*)d_in[10];
    const float* a_dst1 = (const float*)d_in[11];
    const float* W2     = (const float*)d_in[12];
    const float* a_src2 = (const float*)d_in[13];
    const float* a_dst2 = (const float*)d_in[14];
    const float* Wr     = (const float*)d_in[15];
    const float* a_srcr = (const float*)d_in[16];
    const float* a_dstr = (const float*)d_in[17];
    const float* w_fc1  = (const float*)d_in[18];
    const float* b_fc1  = (const float*)d_in[19];
    const float* prelu1 = (const float*)d_in[20];
    const float* w_fc2  = (const float*)d_in[21];
    const float* b_fc2  = (const float*)d_in[22];

    const int N = 100000, E = 800000, M = 5000, ER = 40000;

    float* ws = (float*)d_ws;
    float* h1     = ws;                       // 6,400,000
    float* h2     = h1 + 6400000;             // 6,400,000
    float* attS   = h2 + 6400000;             // 800,000
    float* attD   = attS + 800000;            // 800,000
    float* alphaS = attD + 800000;            // 800,000
    float* mol    = alphaS + 800000;          // 320,000
    float* molr   = mol + 320000;             // 320,000
    float* feat   = molr + 320000;            // 131,072
    float* hm     = feat + 131072;            // 524,288
    float* Vsrc   = hm + 524288;              // 512
    float* Vdst   = Vsrc + 512;               // 512
    int* rowptr   = (int*)(Vdst + 512);       // 100,008
    int* cnt      = rowptr + 100008;          // 100,000
    int* incl     = cnt + 100000;             // 100,000
    int* bsum     = incl + 100000;            // 512
    int* cursor   = bsum + 512;               // 100,000
    int* perm     = cursor + 100000;          // 800,000
    float* hWbuf  = (float*)(perm + 800000);  // rest: up to 8*N*64

    size_t usedFloats = (size_t)(hWbuf - ws);
    size_t availFloats = (ws_size / 4 > usedFloats) ? (ws_size / 4 - usedFloats) : 0;

    auto buildCSR = [&](const int* dstArr, int n, int e) {
        hipMemsetAsync(cnt, 0, (size_t)n * sizeof(int), stream);
        hist_kernel<<<dim3((e + 255) / 256), 256, 0, stream>>>(dstArr, cnt, e);
        int nb = (n + 255) / 256;
        scan1_kernel<<<dim3(nb), 256, 0, stream>>>(cnt, incl, bsum, n);
        scan2_kernel<<<dim3(1), 512, 0, stream>>>(bsum, nb);
        scan3_kernel<<<dim3((n + 256) / 256), 256, 0, stream>>>(incl, cnt, bsum, rowptr, cursor, n, e);
        scatter_kernel<<<dim3((e + 255) / 256), 256, 0, stream>>>(dstArr, cursor, perm, e);
    };

    auto rgat = [&](const float* hin, int n, int e, const int* es, const int* er,
                    const float* W, const float* as, const float* ad,
                    float* agg, int R) {
        compute_v_kernel<<<dim3((R * 64 + 63) / 64), 64, 0, stream>>>(W, as, ad, Vsrc, Vdst, R);
        att_gemm_kernel<<<dim3((n + 63) / 64), 256, 0, stream>>>(hin, Vsrc, Vdst, attS, attD, n, R);
        alpha_kernel<<<dim3(((size_t)n * 64 + 255) / 256), 256, 0, stream>>>(
            rowptr, perm, es, er, attS, attD, alphaS, n, R);

        size_t perRel = (size_t)n * 64;
        int chunk = (int)(availFloats / perRel);
        if (chunk < 1) chunk = 1;
        if (chunk > R) chunk = R;
        for (int r0 = 0; r0 < R; r0 += chunk) {
            int r1 = r0 + chunk; if (r1 > R) r1 = R;
            hw_gemm_kernel<<<dim3((n + 63) / 64, r1 - r0), 256, 0, stream>>>(hin, W, hWbuf, n, r0);
            agg_kernel<<<dim3(((size_t)n * 64 + 255) / 256), 256, 0, stream>>>(
                rowptr, perm, es, er, alphaS, hWbuf, agg, n, n, r0, r1, r1 == R ? 1 : 0);
        }
    };

    // ---- atom graph CSR (shared by both atom layers) ----
    buildCSR(edge_dst, N, E);
    rgat(node_feats, N, E, edge_src, edge_rel, W1, a_src1, a_dst1, h1, 8);
    rgat(h1,         N, E, edge_src, edge_rel, W2, a_src2, a_dst2, h2, 8);

    // ---- molecule pooling ----
    hipMemsetAsync(mol, 0, (size_t)M * 64 * sizeof(float), stream);
    seg_sum64_kernel<<<dim3(((size_t)N * 64 + 255) / 256), 256, 0, stream>>>(h2, node2mol, mol, N);

    // ---- reaction-graph RGAT ----
    buildCSR(rxn_dst, M, ER);
    rgat(mol, M, ER, rxn_src, rxn_rel, Wr, a_srcr, a_dstr, molr, 4);

    // ---- reaction readout ----
    hipMemsetAsync(feat, 0, (size_t)1024 * 128 * sizeof(float), stream);
    readout_kernel<<<dim3(((size_t)M * 64 + 255) / 256), 256, 0, stream>>>(molr, mol, mol2rxn, feat, M);

    // ---- MLP head: tiled GEMMs ----
    fc_gemm_kernel<<<dim3(8, 16), 256, 0, stream>>>(feat, w_fc1, b_fc1, prelu1, hm, 1024, 512, 128, 1);
    fc_gemm_kernel<<<dim3(11, 16), 256, 0, stream>>>(hm, w_fc2, b_fc2, nullptr, (float*)d_out, 1024, 703, 512, 0);
}

// Round 7
// 684.703 us; speedup vs baseline: 5.4788x; 1.2678x over previous
//
#include <hip/hip_runtime.h>
#include <math.h>

#define NEG_SLOPE 0.2f

typedef __attribute__((ext_vector_type(8))) short short8;
typedef __attribute__((ext_vector_type(4))) float float4v;

__device__ __forceinline__ void atomAddF(float* p, float v) {
    unsafeAtomicAdd(p, v);   // HW global_atomic_add_f32 on gfx950
}
__device__ __forceinline__ unsigned short f2bf(float f) {
    unsigned u = __float_as_uint(f);
    unsigned r = (u + 0x7FFFu + ((u >> 16) & 1u)) >> 16;   // RNE
    return (unsigned short)r;
}
__device__ __forceinline__ float bf2f(unsigned short b) {
    return __uint_as_float((unsigned)b << 16);
}

// ================= CSR build (counting sort by dst) =================
__global__ void hist_kernel(const int* __restrict__ dst, int* __restrict__ cnt, int E) {
    int e = blockIdx.x * blockDim.x + threadIdx.x;
    if (e < E) atomicAdd(&cnt[dst[e]], 1);
}

__global__ void scan1_kernel(const int* __restrict__ cnt, int* __restrict__ incl,
                             int* __restrict__ bsum, int n) {
    __shared__ int s[256];
    int t = threadIdx.x, i = blockIdx.x * 256 + t;
    int v = (i < n) ? cnt[i] : 0;
    s[t] = v; __syncthreads();
    for (int o = 1; o < 256; o <<= 1) {
        int u = (t >= o) ? s[t - o] : 0;
        __syncthreads(); s[t] += u; __syncthreads();
    }
    if (i < n) incl[i] = s[t];
    if (t == 255) bsum[blockIdx.x] = s[255];
}

__global__ void scan2_kernel(int* __restrict__ bsum, int nb) {
    __shared__ int s[512];
    int t = threadIdx.x;
    int v = (t < nb) ? bsum[t] : 0;
    s[t] = v; __syncthreads();
    for (int o = 1; o < 512; o <<= 1) {
        int u = (t >= o) ? s[t - o] : 0;
        __syncthreads(); s[t] += u; __syncthreads();
    }
    if (t < nb) bsum[t] = s[t] - v;   // exclusive
}

__global__ void scan3_kernel(const int* __restrict__ incl, const int* __restrict__ cnt,
                             const int* __restrict__ bsum, int* __restrict__ rowptr,
                             int* __restrict__ cursor, int n, int E) {
    int i = blockIdx.x * blockDim.x + threadIdx.x;
    if (i < n) {
        int v = incl[i] - cnt[i] + bsum[i >> 8];
        rowptr[i] = v; cursor[i] = v;
    } else if (i == n) {
        rowptr[n] = E;
    }
}

__global__ void scatter_kernel(const int* __restrict__ dst, int* __restrict__ cursor,
                               int* __restrict__ perm, int E) {
    int e = blockIdx.x * blockDim.x + threadIdx.x;
    if (e < E) { int pos = atomicAdd(&cursor[dst[e]], 1); perm[pos] = e; }
}

// ================= RGAT =================
__global__ void compute_v_kernel(const float* __restrict__ W,
                                 const float* __restrict__ a_src,
                                 const float* __restrict__ a_dst,
                                 float* __restrict__ Vsrc, float* __restrict__ Vdst,
                                 int R) {
    int idx = blockIdx.x * blockDim.x + threadIdx.x;   // r*64+d
    if (idx >= R * 64) return;
    int r = idx >> 6;
    const float* Wr = W + idx * 64;
    const float* as = a_src + r * 64;
    const float* ad = a_dst + r * 64;
    float s = 0.f, t = 0.f;
    for (int e = 0; e < 64; e++) { float w = Wr[e]; s = fmaf(w, as[e], s); t = fmaf(w, ad[e], t); }
    Vsrc[idx] = s; Vdst[idx] = t;
}

// attS[n*R+r] = h[n,:] . Vsrc[r,:]  -- skinny GEMM, 64-node LDS tile (fp32 path)
#define HPAD 68
__global__ __launch_bounds__(256) void att_gemm_kernel(
        const float* __restrict__ h,
        const float* __restrict__ Vsrc, const float* __restrict__ Vdst,
        float* __restrict__ attS, float* __restrict__ attD,
        int N, int R) {
    __shared__ float hl[64 * HPAD];
    __shared__ float Vs[8 * HPAD];
    __shared__ float Vd[8 * HPAD];
    int t = threadIdx.x;
    int n0 = blockIdx.x * 64;

    {
        const float4* hg = (const float4*)h;
#pragma unroll
        for (int i = 0; i < 4; i++) {
            int idx = t + i * 256;
            int row = idx >> 4, col4 = idx & 15;
            int node = n0 + row;
            float4 v = (node < N) ? hg[(size_t)node * 16 + col4] : float4{0.f, 0.f, 0.f, 0.f};
            *(float4*)&hl[row * HPAD + col4 * 4] = v;
        }
    }
    for (int i = t; i < R * 64; i += 256) {
        int r = i >> 6, d = i & 63;
        Vs[r * HPAD + d] = Vsrc[i];
        Vd[r * HPAD + d] = Vdst[i];
    }
    __syncthreads();

    for (int p = t; p < 64 * R; p += 256) {
        int node = p / R, r = p - node * R;
        const float4* hp = (const float4*)&hl[node * HPAD];
        const float4* sp = (const float4*)&Vs[r * HPAD];
        const float4* dp = (const float4*)&Vd[r * HPAD];
        float s = 0.f, dd = 0.f;
#pragma unroll
        for (int d4 = 0; d4 < 16; d4++) {
            float4 hv = hp[d4], sv = sp[d4], dv = dp[d4];
            s  = fmaf(hv.x, sv.x, s);  s  = fmaf(hv.y, sv.y, s);
            s  = fmaf(hv.z, sv.z, s);  s  = fmaf(hv.w, sv.w, s);
            dd = fmaf(hv.x, dv.x, dd); dd = fmaf(hv.y, dv.y, dd);
            dd = fmaf(hv.z, dv.z, dd); dd = fmaf(hv.w, dv.w, dd);
        }
        int gn = n0 + node;
        if (gn < N) { attS[(size_t)gn * R + r] = s; attD[(size_t)gn * R + r] = dd; }
    }
}

__global__ __launch_bounds__(256) void alpha_kernel(
        const int* __restrict__ rowptr, const int* __restrict__ perm,
        const int* __restrict__ src, const int* __restrict__ rel,
        const float* __restrict__ attS, const float* __restrict__ attD,
        float* __restrict__ alphaS, int n, int R) {
    int g = blockIdx.x * blockDim.x + threadIdx.x;
    int wv = g >> 6, lane = g & 63;
    if (wv >= n) return;
    int start = rowptr[wv], end = rowptr[wv + 1];
    int deg = end - start;
    if (deg <= 0) return;
    if (deg <= 64) {
        int i = start + lane;
        bool act = i < end;
        float s = -INFINITY;
        if (act) {
            int e = perm[i]; int r = rel[e];
            float sc = attS[src[e] * R + r] + attD[wv * R + r];
            s = sc > 0.f ? sc : NEG_SLOPE * sc;
        }
        float m = s;
        for (int o = 32; o; o >>= 1) m = fmaxf(m, __shfl_xor(m, o));
        float ex = act ? expf(s - m) : 0.f;
        float sum = ex;
        for (int o = 32; o; o >>= 1) sum += __shfl_xor(sum, o);
        float inv = 1.f / (sum + 1e-9f);
        if (act) alphaS[i] = ex * inv;
    } else {
        float m = -INFINITY;
        for (int base = start; base < end; base += 64) {
            int i = base + lane;
            if (i < end) {
                int e = perm[i]; int r = rel[e];
                float sc = attS[src[e] * R + r] + attD[wv * R + r];
                sc = sc > 0.f ? sc : NEG_SLOPE * sc;
                alphaS[i] = sc;
                m = fmaxf(m, sc);
            }
        }
        for (int o = 32; o; o >>= 1) m = fmaxf(m, __shfl_xor(m, o));
        float sum = 0.f;
        for (int base = start; base < end; base += 64) {
            int i = base + lane;
            if (i < end) { float ex = expf(alphaS[i] - m); alphaS[i] = ex; sum += ex; }
        }
        for (int o = 32; o; o >>= 1) sum += __shfl_xor(sum, o);
        float inv = 1.f / (sum + 1e-9f);
        for (int base = start; base < end; base += 64) {
            int i = base + lane;
            if (i < end) alphaS[i] *= inv;
        }
    }
}

// hW[rl,n,e] = sum_d h[n,d]*W[r,d,e] via bf16 MFMA; output stored bf16.
// Fragment layouts (measured m89/m120): A[m=lane&15][k=8*quad+j],
// B[n=lane&15][k=8*quad+j], D[row=4*quad+reg][col=lane&15].
#define BSTRIDE 72   // bf16 units per LDS row: 2-way bank aliasing only
__global__ __launch_bounds__(256) void hw_gemm_mfma_kernel(
        const float* __restrict__ h, const float* __restrict__ W,
        unsigned short* __restrict__ hWb, int N, int r0) {
    __shared__ unsigned short hb[64 * BSTRIDE];   // h tile, [node][k]
    __shared__ unsigned short wt[64 * BSTRIDE];   // W^T,   [e][k]
    int t = threadIdx.x;
    int n0 = blockIdx.x * 64;
    int r = r0 + blockIdx.y;

    // stage h tile -> bf16
    {
        const float4* hg = (const float4*)h;
#pragma unroll
        for (int i = 0; i < 4; i++) {
            int idx = t + i * 256;               // 0..1023 float4s
            int row = idx >> 4, c4 = idx & 15;
            int node = n0 + row;
            float4 v = (node < N) ? hg[(size_t)node * 16 + c4] : float4{0.f, 0.f, 0.f, 0.f};
            ushort4 b;
            b.x = f2bf(v.x); b.y = f2bf(v.y); b.z = f2bf(v.z); b.w = f2bf(v.w);
            *(ushort4*)&hb[row * BSTRIDE + c4 * 4] = b;
        }
    }
    // stage W^T -> bf16 (read W[k][e] coalesced, write transposed)
    {
        const float4* Wg = (const float4*)(W + (size_t)r * 4096);
#pragma unroll
        for (int i = 0; i < 4; i++) {
            int idx = t + i * 256;
            int k = idx >> 4, e4 = (idx & 15) * 4;
            float4 v = Wg[idx];
            wt[(e4 + 0) * BSTRIDE + k] = f2bf(v.x);
            wt[(e4 + 1) * BSTRIDE + k] = f2bf(v.y);
            wt[(e4 + 2) * BSTRIDE + k] = f2bf(v.z);
            wt[(e4 + 3) * BSTRIDE + k] = f2bf(v.w);
        }
    }
    __syncthreads();

    int w = t >> 6, lane = t & 63;
    int quad = lane >> 4, m = lane & 15;
    int arow = w * 16 + m;
    short8 a0 = *(const short8*)&hb[arow * BSTRIDE + quad * 8];        // k 0..31
    short8 a1 = *(const short8*)&hb[arow * BSTRIDE + 32 + quad * 8];   // k 32..63

    size_t outBase = ((size_t)blockIdx.y * N + n0 + w * 16) * 64;
#pragma unroll
    for (int c = 0; c < 4; c++) {
        short8 b0 = *(const short8*)&wt[(c * 16 + m) * BSTRIDE + quad * 8];
        short8 b1 = *(const short8*)&wt[(c * 16 + m) * BSTRIDE + 32 + quad * 8];
        float4v acc = {0.f, 0.f, 0.f, 0.f};
        acc = __builtin_amdgcn_mfma_f32_16x16x32_bf16(a0, b0, acc, 0, 0, 0);
        acc = __builtin_amdgcn_mfma_f32_16x16x32_bf16(a1, b1, acc, 0, 0, 0);
#pragma unroll
        for (int reg = 0; reg < 4; reg++) {
            int node = n0 + w * 16 + quad * 4 + reg;
            if (node < N)
                hWb[outBase + (size_t)(quad * 4 + reg) * 64 + c * 16 + m] = f2bf(acc[reg]);
        }
    }
}

// dst-centric aggregation from bf16 hW: one wave per dst, no atomics. ELU fused.
__global__ __launch_bounds__(256) void agg_kernel(
        const int* __restrict__ rowptr, const int* __restrict__ perm,
        const int* __restrict__ src, const int* __restrict__ rel,
        const float* __restrict__ alphaS, const unsigned short* __restrict__ hWb,
        float* __restrict__ agg, int n, int N, int r0, int r1, int last) {
    int g = blockIdx.x * blockDim.x + threadIdx.x;
    int wv = g >> 6, lane = g & 63;
    if (wv >= n) return;
    int start = rowptr[wv], end = rowptr[wv + 1];
    float acc = (r0 == 0) ? 0.f : agg[(size_t)wv * 64 + lane];

    int i0 = start + lane;
    int rL = -1, sL = 0; float aL = 0.f;
    if (i0 < end) {
        int e = perm[i0];
        rL = rel[e]; sL = src[e]; aL = alphaS[i0];
    }
    int cnt = min(end - start, 64);
    for (int k = 0; k < cnt; k++) {
        int r = __shfl(rL, k); int s = __shfl(sL, k); float a = __shfl(aL, k);
        if (r >= r0 && r < r1)
            acc = fmaf(a, bf2f(hWb[((size_t)(r - r0) * N + s) * 64 + lane]), acc);
    }
    for (int i = start + 64; i < end; i++) {
        int e = perm[i]; int r = rel[e];
        if (r >= r0 && r < r1)
            acc = fmaf(alphaS[i], bf2f(hWb[((size_t)(r - r0) * N + src[e]) * 64 + lane]), acc);
    }
    if (last) acc = acc > 0.f ? acc : expm1f(acc);
    agg[(size_t)wv * 64 + lane] = acc;
}

// ================= pooling / readout =================
__global__ void seg_sum64_kernel(const float* __restrict__ h, const int* __restrict__ seg,
                                 float* __restrict__ out, int N) {
    int i = blockIdx.x * blockDim.x + threadIdx.x;
    if (i >= N * 64) return;
    int n = i >> 6, d = i & 63;
    atomAddF(&out[seg[n] * 64 + d], h[i]);
}

__global__ void readout_kernel(const float* __restrict__ molr, const float* __restrict__ mol,
                               const int* __restrict__ mol2rxn, float* __restrict__ feat, int M) {
    int i = blockIdx.x * blockDim.x + threadIdx.x;
    if (i >= M * 64) return;
    int m = i >> 6, d = i & 63;
    int b = mol2rxn[m];
    atomAddF(&feat[b * 128 + d], molr[i]);
    atomAddF(&feat[b * 128 + 64 + d], mol[i]);
}

// ================= MLP head: LDS-tiled GEMM =================
#define APAD 36
__global__ __launch_bounds__(256) void fc_gemm_kernel(
        const float* __restrict__ A, const float* __restrict__ B,
        const float* __restrict__ bias, const float* __restrict__ prelu,
        float* __restrict__ C, int M, int N, int K, int mode) {
    __shared__ float Al[64 * APAD];
    __shared__ float Bl[32 * 64];
    int t = threadIdx.x;
    int n0 = blockIdx.x * 64, m0 = blockIdx.y * 64;
    int e4 = (t & 15) * 4;
    int n4 = (t >> 4) * 4;
    float acc[4][4] = {};

    for (int k0 = 0; k0 < K; k0 += 32) {
        {
            const float4* Ag = (const float4*)A;
#pragma unroll
            for (int i = 0; i < 2; i++) {
                int idx = t + i * 256;
                int row = idx >> 3, c4 = idx & 7;
                float4 v = Ag[(size_t)(m0 + row) * (K >> 2) + (k0 >> 2) + c4];
                float* p = &Al[row * APAD + c4 * 4];
                p[0] = v.x; p[1] = v.y; p[2] = v.z; p[3] = v.w;
            }
        }
        {
#pragma unroll
            for (int i = 0; i < 2; i++) {
                int idx = t + i * 256;
                int kk = idx >> 4, c4 = (idx & 15) * 4;
                int col = n0 + c4;
                float4 v;
                const float* Brow = B + (size_t)(k0 + kk) * N;
                if (col + 3 < N) v = *(const float4*)&Brow[col];
                else {
                    v.x = (col + 0 < N) ? Brow[col + 0] : 0.f;
                    v.y = (col + 1 < N) ? Brow[col + 1] : 0.f;
                    v.z = (col + 2 < N) ? Brow[col + 2] : 0.f;
                    v.w = 0.f;
                }
                *(float4*)&Bl[kk * 64 + c4] = v;
            }
        }
        __syncthreads();
        for (int d = 0; d < 32; d += 4) {
            float4 wv[4], hv[4];
#pragma unroll
            for (int dd = 0; dd < 4; dd++) wv[dd] = *(const float4*)&Bl[(d + dd) * 64 + e4];
#pragma unroll
            for (int i = 0; i < 4; i++) hv[i] = *(const float4*)&Al[(n4 + i) * APAD + d];
#pragma unroll
            for (int i = 0; i < 4; i++) {
                const float hvv[4] = {hv[i].x, hv[i].y, hv[i].z, hv[i].w};
#pragma unroll
                for (int dd = 0; dd < 4; dd++) {
                    const float* wp = (const float*)&wv[dd];
#pragma unroll
                    for (int j = 0; j < 4; j++) acc[i][j] = fmaf(hvv[dd], wp[j], acc[i][j]);
                }
            }
        }
        __syncthreads();
    }

    float p = mode ? *prelu : 0.f;
#pragma unroll
    for (int i = 0; i < 4; i++) {
        int row = m0 + n4 + i;
#pragma unroll
        for (int j = 0; j < 4; j++) {
            int col = n0 + e4 + j;
            if (col < N) {
                float v = acc[i][j] + bias[col];
                if (mode) v = v > 0.f ? v : p * v;
                C[(size_t)row * N + col] = v;
            }
        }
    }
}

// ================= launch =================
extern "C" void kernel_launch(void* const* d_in, const int* in_sizes, int n_in,
                              void* d_out, int out_size, void* d_ws, size_t ws_size,
                              hipStream_t stream) {
    const float* node_feats = (const float*)d_in[0];
    const int*   edge_src   = (const int*)d_in[1];
    const int*   edge_dst   = (const int*)d_in[2];
    const int*   edge_rel   = (const int*)d_in[3];
    const int*   node2mol   = (const int*)d_in[4];
    const int*   rxn_src    = (const int*)d_in[5];
    const int*   rxn_dst    = (const int*)d_in[6];
    const int*   rxn_rel    = (const int*)d_in[7];
    const int*   mol2rxn    = (const int*)d_in[8];
    const float* W1     = (const float*)d_in[9];
    const float* a_src1 = (const float*)d_in[10];
    const float* a_dst1 = (const float*)d_in[11];
    const float* W2     = (const float*)d_in[12];
    const float* a_src2 = (const float*)d_in[13];
    const float* a_dst2 = (const float*)d_in[14];
    const float* Wr     = (const float*)d_in[15];
    const float* a_srcr = (const float*)d_in[16];
    const float* a_dstr = (const float*)d_in[17];
    const float* w_fc1  = (const float*)d_in[18];
    const float* b_fc1  = (const float*)d_in[19];
    const float* prelu1 = (const float*)d_in[20];
    const float* w_fc2  = (const float*)d_in[21];
    const float* b_fc2  = (const float*)d_in[22];

    const int N = 100000, E = 800000, M = 5000, ER = 40000;

    float* ws = (float*)d_ws;
    float* h1     = ws;                       // 6,400,000
    float* h2     = h1 + 6400000;             // 6,400,000
    float* attS   = h2 + 6400000;             // 800,000
    float* attD   = attS + 800000;            // 800,000
    float* alphaS = attD + 800000;            // 800,000
    float* mol    = alphaS + 800000;          // 320,000
    float* molr   = mol + 320000;             // 320,000
    float* feat   = molr + 320000;            // 131,072
    float* hm     = feat + 131072;            // 524,288
    float* Vsrc   = hm + 524288;              // 512
    float* Vdst   = Vsrc + 512;               // 512
    int* rowptr   = (int*)(Vdst + 512);       // 100,008
    int* cnt      = rowptr + 100008;          // 100,000
    int* incl     = cnt + 100000;             // 100,000
    int* bsum     = incl + 100000;            // 512
    int* cursor   = bsum + 512;               // 100,000
    int* perm     = cursor + 100000;          // 800,000
    unsigned short* hWb = (unsigned short*)(perm + 800000);  // bf16 hW (chunked)

    size_t usedBytes = (size_t)((char*)hWb - (char*)d_ws);
    size_t availUshorts = (ws_size > usedBytes) ? (ws_size - usedBytes) / 2 : 0;

    auto buildCSR = [&](const int* dstArr, int n, int e) {
        hipMemsetAsync(cnt, 0, (size_t)n * sizeof(int), stream);
        hist_kernel<<<dim3((e + 255) / 256), 256, 0, stream>>>(dstArr, cnt, e);
        int nb = (n + 255) / 256;
        scan1_kernel<<<dim3(nb), 256, 0, stream>>>(cnt, incl, bsum, n);
        scan2_kernel<<<dim3(1), 512, 0, stream>>>(bsum, nb);
        scan3_kernel<<<dim3((n + 256) / 256), 256, 0, stream>>>(incl, cnt, bsum, rowptr, cursor, n, e);
        scatter_kernel<<<dim3((e + 255) / 256), 256, 0, stream>>>(dstArr, cursor, perm, e);
    };

    auto rgat = [&](const float* hin, int n, int e, const int* es, const int* er,
                    const float* W, const float* as, const float* ad,
                    float* agg, int R) {
        compute_v_kernel<<<dim3((R * 64 + 63) / 64), 64, 0, stream>>>(W, as, ad, Vsrc, Vdst, R);
        att_gemm_kernel<<<dim3((n + 63) / 64), 256, 0, stream>>>(hin, Vsrc, Vdst, attS, attD, n, R);
        alpha_kernel<<<dim3(((size_t)n * 64 + 255) / 256), 256, 0, stream>>>(
            rowptr, perm, es, er, attS, attD, alphaS, n, R);

        size_t perRel = (size_t)n * 64;   // ushorts per relation
        int chunk = (int)(availUshorts / perRel);
        if (chunk < 1) chunk = 1;
        if (chunk > R) chunk = R;
        for (int r0 = 0; r0 < R; r0 += chunk) {
            int r1 = r0 + chunk; if (r1 > R) r1 = R;
            hw_gemm_mfma_kernel<<<dim3((n + 63) / 64, r1 - r0), 256, 0, stream>>>(hin, W, hWb, n, r0);
            agg_kernel<<<dim3(((size_t)n * 64 + 255) / 256), 256, 0, stream>>>(
                rowptr, perm, es, er, alphaS, hWb, agg, n, n, r0, r1, r1 == R ? 1 : 0);
        }
    };

    // ---- atom graph CSR (shared by both atom layers) ----
    buildCSR(edge_dst, N, E);
    rgat(node_feats, N, E, edge_src, edge_rel, W1, a_src1, a_dst1, h1, 8);
    rgat(h1,         N, E, edge_src, edge_rel, W2, a_src2, a_dst2, h2, 8);

    // ---- molecule pooling ----
    hipMemsetAsync(mol, 0, (size_t)M * 64 * sizeof(float), stream);
    seg_sum64_kernel<<<dim3(((size_t)N * 64 + 255) / 256), 256, 0, stream>>>(h2, node2mol, mol, N);

    // ---- reaction-graph RGAT ----
    buildCSR(rxn_dst, M, ER);
    rgat(mol, M, ER, rxn_src, rxn_rel, Wr, a_srcr, a_dstr, molr, 4);

    // ---- reaction readout ----
    hipMemsetAsync(feat, 0, (size_t)1024 * 128 * sizeof(float), stream);
    readout_kernel<<<dim3(((size_t)M * 64 + 255) / 256), 256, 0, stream>>>(molr, mol, mol2rxn, feat, M);

    // ---- MLP head: tiled GEMMs ----
    fc_gemm_kernel<<<dim3(8, 16), 256, 0, stream>>>(feat, w_fc1, b_fc1, prelu1, hm, 1024, 512, 128, 1);
    fc_gemm_kernel<<<dim3(11, 16), 256, 0, stream>>>(hm, w_fc2, b_fc2, nullptr, (float*)d_out, 1024, 703, 512, 0);
}

// Round 8
// 630.356 us; speedup vs baseline: 5.9511x; 1.0862x over previous
//
#include <hip/hip_runtime.h>
#include <math.h>

#define NEG_SLOPE 0.2f

typedef __attribute__((ext_vector_type(8))) short short8;
typedef __attribute__((ext_vector_type(4))) float float4v;

__device__ __forceinline__ void atomAddF(float* p, float v) {
    unsafeAtomicAdd(p, v);   // HW global_atomic_add_f32 on gfx950
}
__device__ __forceinline__ unsigned short f2bf(float f) {
    unsigned u = __float_as_uint(f);
    unsigned r = (u + 0x7FFFu + ((u >> 16) & 1u)) >> 16;   // RNE
    return (unsigned short)r;
}
__device__ __forceinline__ float bf2f(unsigned short b) {
    return __uint_as_float((unsigned)b << 16);
}

// ================= CSR build (counting sort by dst) =================
__global__ void hist_kernel(const int* __restrict__ dst, int* __restrict__ cnt, int E) {
    int e = blockIdx.x * blockDim.x + threadIdx.x;
    if (e < E) atomicAdd(&cnt[dst[e]], 1);
}

__global__ void scan1_kernel(const int* __restrict__ cnt, int* __restrict__ incl,
                             int* __restrict__ bsum, int n) {
    __shared__ int s[256];
    int t = threadIdx.x, i = blockIdx.x * 256 + t;
    int v = (i < n) ? cnt[i] : 0;
    s[t] = v; __syncthreads();
    for (int o = 1; o < 256; o <<= 1) {
        int u = (t >= o) ? s[t - o] : 0;
        __syncthreads(); s[t] += u; __syncthreads();
    }
    if (i < n) incl[i] = s[t];
    if (t == 255) bsum[blockIdx.x] = s[255];
}

__global__ void scan2_kernel(int* __restrict__ bsum, int nb) {
    __shared__ int s[512];
    int t = threadIdx.x;
    int v = (t < nb) ? bsum[t] : 0;
    s[t] = v; __syncthreads();
    for (int o = 1; o < 512; o <<= 1) {
        int u = (t >= o) ? s[t - o] : 0;
        __syncthreads(); s[t] += u; __syncthreads();
    }
    if (t < nb) bsum[t] = s[t] - v;   // exclusive
}

__global__ void scan3_kernel(const int* __restrict__ incl, const int* __restrict__ cnt,
                             const int* __restrict__ bsum, int* __restrict__ rowptr,
                             int* __restrict__ cursor, int n, int E) {
    int i = blockIdx.x * blockDim.x + threadIdx.x;
    if (i < n) {
        int v = incl[i] - cnt[i] + bsum[i >> 8];
        rowptr[i] = v; cursor[i] = v;
    } else if (i == n) {
        rowptr[n] = E;
    }
}

__global__ void scatter_kernel(const int* __restrict__ dst, int* __restrict__ cursor,
                               int* __restrict__ perm, int E) {
    int e = blockIdx.x * blockDim.x + threadIdx.x;
    if (e < E) { int pos = atomicAdd(&cursor[dst[e]], 1); perm[pos] = e; }
}

// packed[i] = (rel[perm[i]]<<24) | src[perm[i]]  (src < 2^24)
__global__ void pack_kernel(const int* __restrict__ perm, const int* __restrict__ rel,
                            const int* __restrict__ src, unsigned* __restrict__ packed, int E) {
    int i = blockIdx.x * blockDim.x + threadIdx.x;
    if (i < E) {
        int e = perm[i];
        packed[i] = ((unsigned)rel[e] << 24) | (unsigned)src[e];
    }
}

// ================= RGAT =================
__global__ void compute_v_kernel(const float* __restrict__ W,
                                 const float* __restrict__ a_src,
                                 const float* __restrict__ a_dst,
                                 float* __restrict__ Vsrc, float* __restrict__ Vdst,
                                 int R) {
    int idx = blockIdx.x * blockDim.x + threadIdx.x;   // r*64+d
    if (idx >= R * 64) return;
    int r = idx >> 6;
    const float* Wr = W + idx * 64;
    const float* as = a_src + r * 64;
    const float* ad = a_dst + r * 64;
    float s = 0.f, t = 0.f;
    for (int e = 0; e < 64; e++) { float w = Wr[e]; s = fmaf(w, as[e], s); t = fmaf(w, ad[e], t); }
    Vsrc[idx] = s; Vdst[idx] = t;
}

// attS[n*R+r] = h[n,:] . Vsrc[r,:]  -- skinny GEMM, 64-node LDS tile (fp32)
#define HPAD 68
__global__ __launch_bounds__(256) void att_gemm_kernel(
        const float* __restrict__ h,
        const float* __restrict__ Vsrc, const float* __restrict__ Vdst,
        float* __restrict__ attS, float* __restrict__ attD,
        int N, int R) {
    __shared__ float hl[64 * HPAD];
    __shared__ float Vs[8 * HPAD];
    __shared__ float Vd[8 * HPAD];
    int t = threadIdx.x;
    int n0 = blockIdx.x * 64;

    {
        const float4* hg = (const float4*)h;
#pragma unroll
        for (int i = 0; i < 4; i++) {
            int idx = t + i * 256;
            int row = idx >> 4, col4 = idx & 15;
            int node = n0 + row;
            float4 v = (node < N) ? hg[(size_t)node * 16 + col4] : float4{0.f, 0.f, 0.f, 0.f};
            *(float4*)&hl[row * HPAD + col4 * 4] = v;
        }
    }
    for (int i = t; i < R * 64; i += 256) {
        int r = i >> 6, d = i & 63;
        Vs[r * HPAD + d] = Vsrc[i];
        Vd[r * HPAD + d] = Vdst[i];
    }
    __syncthreads();

    for (int p = t; p < 64 * R; p += 256) {
        int node = p / R, r = p - node * R;
        const float4* hp = (const float4*)&hl[node * HPAD];
        const float4* sp = (const float4*)&Vs[r * HPAD];
        const float4* dp = (const float4*)&Vd[r * HPAD];
        float s = 0.f, dd = 0.f;
#pragma unroll
        for (int d4 = 0; d4 < 16; d4++) {
            float4 hv = hp[d4], sv = sp[d4], dv = dp[d4];
            s  = fmaf(hv.x, sv.x, s);  s  = fmaf(hv.y, sv.y, s);
            s  = fmaf(hv.z, sv.z, s);  s  = fmaf(hv.w, sv.w, s);
            dd = fmaf(hv.x, dv.x, dd); dd = fmaf(hv.y, dv.y, dd);
            dd = fmaf(hv.z, dv.z, dd); dd = fmaf(hv.w, dv.w, dd);
        }
        int gn = n0 + node;
        if (gn < N) { attS[(size_t)gn * R + r] = s; attD[(size_t)gn * R + r] = dd; }
    }
}

// hW[rl,n,e] via bf16 MFMA; h tile staged+converted ONCE, loop relations.
// Fragment layouts (measured m89/m120): A[m=lane&15][k=8*quad+j],
// B[n=lane&15][k=8*quad+j], D[row=4*quad+reg][col=lane&15].
#define BSTRIDE 72
__global__ __launch_bounds__(256) void hw_gemm_mfma_kernel(
        const float* __restrict__ h, const float* __restrict__ W,
        unsigned short* __restrict__ hWb, int N, int r0, int r1) {
    __shared__ unsigned short hb[64 * BSTRIDE];
    __shared__ unsigned short wt[64 * BSTRIDE];
    int t = threadIdx.x;
    int n0 = blockIdx.x * 64;

    // stage h tile -> bf16 (once)
    {
        const float4* hg = (const float4*)h;
#pragma unroll
        for (int i = 0; i < 4; i++) {
            int idx = t + i * 256;
            int row = idx >> 4, c4 = idx & 15;
            int node = n0 + row;
            float4 v = (node < N) ? hg[(size_t)node * 16 + c4] : float4{0.f, 0.f, 0.f, 0.f};
            ushort4 b;
            b.x = f2bf(v.x); b.y = f2bf(v.y); b.z = f2bf(v.z); b.w = f2bf(v.w);
            *(ushort4*)&hb[row * BSTRIDE + c4 * 4] = b;
        }
    }
    __syncthreads();

    int w = t >> 6, lane = t & 63;
    int quad = lane >> 4, m = lane & 15;
    int arow = w * 16 + m;
    short8 a0 = *(const short8*)&hb[arow * BSTRIDE + quad * 8];        // k 0..31
    short8 a1 = *(const short8*)&hb[arow * BSTRIDE + 32 + quad * 8];   // k 32..63

    for (int r = r0; r < r1; r++) {
        __syncthreads();   // previous iter's wt reads complete
        {
            const float4* Wg = (const float4*)(W + (size_t)r * 4096);
#pragma unroll
            for (int i = 0; i < 4; i++) {
                int idx = t + i * 256;
                int k = idx >> 4, e4 = (idx & 15) * 4;
                float4 v = Wg[idx];
                wt[(e4 + 0) * BSTRIDE + k] = f2bf(v.x);
                wt[(e4 + 1) * BSTRIDE + k] = f2bf(v.y);
                wt[(e4 + 2) * BSTRIDE + k] = f2bf(v.z);
                wt[(e4 + 3) * BSTRIDE + k] = f2bf(v.w);
            }
        }
        __syncthreads();

        size_t outBase = ((size_t)(r - r0) * N + n0 + w * 16) * 64;
#pragma unroll
        for (int c = 0; c < 4; c++) {
            short8 b0 = *(const short8*)&wt[(c * 16 + m) * BSTRIDE + quad * 8];
            short8 b1 = *(const short8*)&wt[(c * 16 + m) * BSTRIDE + 32 + quad * 8];
            float4v acc = {0.f, 0.f, 0.f, 0.f};
            acc = __builtin_amdgcn_mfma_f32_16x16x32_bf16(a0, b0, acc, 0, 0, 0);
            acc = __builtin_amdgcn_mfma_f32_16x16x32_bf16(a1, b1, acc, 0, 0, 0);
#pragma unroll
            for (int reg = 0; reg < 4; reg++) {
                int node = n0 + w * 16 + quad * 4 + reg;
                if (node < N)
                    hWb[outBase + (size_t)(quad * 4 + reg) * 64 + c * 16 + m] = f2bf(acc[reg]);
            }
        }
    }
}

// fused softmax + aggregation: one wave per dst. packed = (rel<<24)|src in CSR order.
__global__ __launch_bounds__(256) void aggsoft_kernel(
        const int* __restrict__ rowptr, const unsigned* __restrict__ packed,
        const float* __restrict__ attS, const float* __restrict__ attD,
        const unsigned short* __restrict__ hWb, float* __restrict__ agg,
        int n, int N, int R, int r0, int r1, int last) {
    int g = blockIdx.x * blockDim.x + threadIdx.x;
    int wv = g >> 6, lane = g & 63;
    if (wv >= n) return;
    int start = rowptr[wv], end = rowptr[wv + 1];
    int deg = end - start;
    float acc = (r0 == 0) ? 0.f : agg[(size_t)wv * 64 + lane];

    if (deg > 0 && deg <= 64) {
        int i = start + lane;
        bool act = i < end;
        unsigned p = act ? packed[i] : 0u;
        int r = p >> 24, s = p & 0xFFFFFFu;
        float sc = -INFINITY;
        if (act) {
            sc = attS[(size_t)s * R + r] + attD[(size_t)wv * R + r];
            sc = sc > 0.f ? sc : NEG_SLOPE * sc;
        }
        float m = sc;
        for (int o = 32; o; o >>= 1) m = fmaxf(m, __shfl_xor(m, o));
        float ex = act ? expf(sc - m) : 0.f;
        float sum = ex;
        for (int o = 32; o; o >>= 1) sum += __shfl_xor(sum, o);
        float a = ex / (sum + 1e-9f);
        for (int k = 0; k < deg; k++) {
            int rr = __shfl(r, k); int ss = __shfl(s, k); float aa = __shfl(a, k);
            if (rr >= r0 && rr < r1)
                acc = fmaf(aa, bf2f(hWb[((size_t)(rr - r0) * N + ss) * 64 + lane]), acc);
        }
    } else if (deg > 64) {
        // rare fallback: recompute scores in passes
        float m = -INFINITY;
        for (int base = start; base < end; base += 64) {
            int i = base + lane;
            if (i < end) {
                unsigned p = packed[i];
                int r = p >> 24, s = p & 0xFFFFFFu;
                float sc = attS[(size_t)s * R + r] + attD[(size_t)wv * R + r];
                sc = sc > 0.f ? sc : NEG_SLOPE * sc;
                m = fmaxf(m, sc);
            }
        }
        for (int o = 32; o; o >>= 1) m = fmaxf(m, __shfl_xor(m, o));
        float sum = 0.f;
        for (int base = start; base < end; base += 64) {
            int i = base + lane;
            if (i < end) {
                unsigned p = packed[i];
                int r = p >> 24, s = p & 0xFFFFFFu;
                float sc = attS[(size_t)s * R + r] + attD[(size_t)wv * R + r];
                sc = sc > 0.f ? sc : NEG_SLOPE * sc;
                sum += expf(sc - m);
            }
        }
        for (int o = 32; o; o >>= 1) sum += __shfl_xor(sum, o);
        float inv = 1.f / (sum + 1e-9f);
        for (int i = start; i < end; i++) {
            unsigned p = packed[i];              // wave-uniform scalar load
            int r = p >> 24, s = p & 0xFFFFFFu;
            if (r >= r0 && r < r1) {
                float sc = attS[(size_t)s * R + r] + attD[(size_t)wv * R + r];
                sc = sc > 0.f ? sc : NEG_SLOPE * sc;
                float aa = expf(sc - m) * inv;
                acc = fmaf(aa, bf2f(hWb[((size_t)(r - r0) * N + s) * 64 + lane]), acc);
            }
        }
    }
    if (last) acc = acc > 0.f ? acc : expm1f(acc);
    agg[(size_t)wv * 64 + lane] = acc;
}

// ================= pooling / readout =================
__global__ void seg_sum64_kernel(const float* __restrict__ h, const int* __restrict__ seg,
                                 float* __restrict__ out, int N) {
    int i = blockIdx.x * blockDim.x + threadIdx.x;
    if (i >= N * 64) return;
    int n = i >> 6, d = i & 63;
    atomAddF(&out[seg[n] * 64 + d], h[i]);
}

__global__ void readout_kernel(const float* __restrict__ molr, const float* __restrict__ mol,
                               const int* __restrict__ mol2rxn, float* __restrict__ feat, int M) {
    int i = blockIdx.x * blockDim.x + threadIdx.x;
    if (i >= M * 64) return;
    int m = i >> 6, d = i & 63;
    int b = mol2rxn[m];
    atomAddF(&feat[b * 128 + d], molr[i]);
    atomAddF(&feat[b * 128 + 64 + d], mol[i]);
}

// ================= MLP head: LDS-tiled GEMM =================
#define APAD 36
__global__ __launch_bounds__(256) void fc_gemm_kernel(
        const float* __restrict__ A, const float* __restrict__ B,
        const float* __restrict__ bias, const float* __restrict__ prelu,
        float* __restrict__ C, int M, int N, int K, int mode) {
    __shared__ float Al[64 * APAD];
    __shared__ float Bl[32 * 64];
    int t = threadIdx.x;
    int n0 = blockIdx.x * 64, m0 = blockIdx.y * 64;
    int e4 = (t & 15) * 4;
    int n4 = (t >> 4) * 4;
    float acc[4][4] = {};

    for (int k0 = 0; k0 < K; k0 += 32) {
        {
            const float4* Ag = (const float4*)A;
#pragma unroll
            for (int i = 0; i < 2; i++) {
                int idx = t + i * 256;
                int row = idx >> 3, c4 = idx & 7;
                float4 v = Ag[(size_t)(m0 + row) * (K >> 2) + (k0 >> 2) + c4];
                float* p = &Al[row * APAD + c4 * 4];
                p[0] = v.x; p[1] = v.y; p[2] = v.z; p[3] = v.w;
            }
        }
        {
#pragma unroll
            for (int i = 0; i < 2; i++) {
                int idx = t + i * 256;
                int kk = idx >> 4, c4 = (idx & 15) * 4;
                int col = n0 + c4;
                float4 v;
                const float* Brow = B + (size_t)(k0 + kk) * N;
                if (col + 3 < N) v = *(const float4*)&Brow[col];
                else {
                    v.x = (col + 0 < N) ? Brow[col + 0] : 0.f;
                    v.y = (col + 1 < N) ? Brow[col + 1] : 0.f;
                    v.z = (col + 2 < N) ? Brow[col + 2] : 0.f;
                    v.w = 0.f;
                }
                *(float4*)&Bl[kk * 64 + c4] = v;
            }
        }
        __syncthreads();
        for (int d = 0; d < 32; d += 4) {
            float4 wv[4], hv[4];
#pragma unroll
            for (int dd = 0; dd < 4; dd++) wv[dd] = *(const float4*)&Bl[(d + dd) * 64 + e4];
#pragma unroll
            for (int i = 0; i < 4; i++) hv[i] = *(const float4*)&Al[(n4 + i) * APAD + d];
#pragma unroll
            for (int i = 0; i < 4; i++) {
                const float hvv[4] = {hv[i].x, hv[i].y, hv[i].z, hv[i].w};
#pragma unroll
                for (int dd = 0; dd < 4; dd++) {
                    const float* wp = (const float*)&wv[dd];
#pragma unroll
                    for (int j = 0; j < 4; j++) acc[i][j] = fmaf(hvv[dd], wp[j], acc[i][j]);
                }
            }
        }
        __syncthreads();
    }

    float p = mode ? *prelu : 0.f;
#pragma unroll
    for (int i = 0; i < 4; i++) {
        int row = m0 + n4 + i;
#pragma unroll
        for (int j = 0; j < 4; j++) {
            int col = n0 + e4 + j;
            if (col < N) {
                float v = acc[i][j] + bias[col];
                if (mode) v = v > 0.f ? v : p * v;
                C[(size_t)row * N + col] = v;
            }
        }
    }
}

// ================= launch =================
extern "C" void kernel_launch(void* const* d_in, const int* in_sizes, int n_in,
                              void* d_out, int out_size, void* d_ws, size_t ws_size,
                              hipStream_t stream) {
    const float* node_feats = (const float*)d_in[0];
    const int*   edge_src   = (const int*)d_in[1];
    const int*   edge_dst   = (const int*)d_in[2];
    const int*   edge_rel   = (const int*)d_in[3];
    const int*   node2mol   = (const int*)d_in[4];
    const int*   rxn_src    = (const int*)d_in[5];
    const int*   rxn_dst    = (const int*)d_in[6];
    const int*   rxn_rel    = (const int*)d_in[7];
    const int*   mol2rxn    = (const int*)d_in[8];
    const float* W1     = (const float*)d_in[9];
    const float* a_src1 = (const float*)d_in[10];
    const float* a_dst1 = (const float*)d_in[11];
    const float* W2     = (const float*)d_in[12];
    const float* a_src2 = (const float*)d_in[13];
    const float* a_dst2 = (const float*)d_in[14];
    const float* Wr     = (const float*)d_in[15];
    const float* a_srcr = (const float*)d_in[16];
    const float* a_dstr = (const float*)d_in[17];
    const float* w_fc1  = (const float*)d_in[18];
    const float* b_fc1  = (const float*)d_in[19];
    const float* prelu1 = (const float*)d_in[20];
    const float* w_fc2  = (const float*)d_in[21];
    const float* b_fc2  = (const float*)d_in[22];

    const int N = 100000, E = 800000, M = 5000, ER = 40000;

    float* ws = (float*)d_ws;
    float* h1     = ws;                       // 6,400,000
    float* h2     = h1 + 6400000;             // 6,400,000
    float* attS   = h2 + 6400000;             // 800,000
    float* attD   = attS + 800000;            // 800,000
    float* mol    = attD + 800000;            // 320,000
    float* molr   = mol + 320000;             // 320,000
    float* feat   = molr + 320000;            // 131,072
    float* hm     = feat + 131072;            // 524,288
    float* Vsrc   = hm + 524288;              // 512
    float* Vdst   = Vsrc + 512;               // 512
    int* rowptr   = (int*)(Vdst + 512);       // 100,008
    int* cnt      = rowptr + 100008;          // 100,000
    int* incl     = cnt + 100000;             // 100,000
    int* bsum     = incl + 100000;            // 512
    int* cursor   = bsum + 512;               // 100,000
    int* perm     = cursor + 100000;          // 800,000
    unsigned* packed = (unsigned*)(perm + 800000);           // 800,000
    unsigned short* hWb = (unsigned short*)(packed + 800000); // bf16 hW (chunked)

    size_t usedBytes = (size_t)((char*)hWb - (char*)d_ws);
    size_t availUshorts = (ws_size > usedBytes) ? (ws_size - usedBytes) / 2 : 0;

    auto buildCSR = [&](const int* dstArr, const int* srcArr, const int* relArr, int n, int e) {
        hipMemsetAsync(cnt, 0, (size_t)n * sizeof(int), stream);
        hist_kernel<<<dim3((e + 255) / 256), 256, 0, stream>>>(dstArr, cnt, e);
        int nb = (n + 255) / 256;
        scan1_kernel<<<dim3(nb), 256, 0, stream>>>(cnt, incl, bsum, n);
        scan2_kernel<<<dim3(1), 512, 0, stream>>>(bsum, nb);
        scan3_kernel<<<dim3((n + 256) / 256), 256, 0, stream>>>(incl, cnt, bsum, rowptr, cursor, n, e);
        scatter_kernel<<<dim3((e + 255) / 256), 256, 0, stream>>>(dstArr, cursor, perm, e);
        pack_kernel<<<dim3((e + 255) / 256), 256, 0, stream>>>(perm, relArr, srcArr, packed, e);
    };

    auto rgat = [&](const float* hin, int n,
                    const float* W, const float* as, const float* ad,
                    float* agg, int R) {
        compute_v_kernel<<<dim3((R * 64 + 63) / 64), 64, 0, stream>>>(W, as, ad, Vsrc, Vdst, R);
        att_gemm_kernel<<<dim3((n + 63) / 64), 256, 0, stream>>>(hin, Vsrc, Vdst, attS, attD, n, R);

        size_t perRel = (size_t)n * 64;   // ushorts per relation
        int chunk = (int)(availUshorts / perRel);
        if (chunk < 1) chunk = 1;
        if (chunk > R) chunk = R;
        for (int r0 = 0; r0 < R; r0 += chunk) {
            int r1 = r0 + chunk; if (r1 > R) r1 = R;
            hw_gemm_mfma_kernel<<<dim3((n + 63) / 64), 256, 0, stream>>>(hin, W, hWb, n, r0, r1);
            aggsoft_kernel<<<dim3(((size_t)n * 64 + 255) / 256), 256, 0, stream>>>(
                rowptr, packed, attS, attD, hWb, agg, n, n, R, r0, r1, r1 == R ? 1 : 0);
        }
    };

    // ---- atom graph CSR (shared by both atom layers) ----
    buildCSR(edge_dst, edge_src, edge_rel, N, E);
    rgat(node_feats, N, W1, a_src1, a_dst1, h1, 8);
    rgat(h1,         N, W2, a_src2, a_dst2, h2, 8);

    // ---- molecule pooling ----
    hipMemsetAsync(mol, 0, (size_t)M * 64 * sizeof(float), stream);
    seg_sum64_kernel<<<dim3(((size_t)N * 64 + 255) / 256), 256, 0, stream>>>(h2, node2mol, mol, N);

    // ---- reaction-graph RGAT ----
    buildCSR(rxn_dst, rxn_src, rxn_rel, M, ER);
    rgat(mol, M, Wr, a_srcr, a_dstr, molr, 4);

    // ---- reaction readout ----
    hipMemsetAsync(feat, 0, (size_t)1024 * 128 * sizeof(float), stream);
    readout_kernel<<<dim3(((size_t)M * 64 + 255) / 256), 256, 0, stream>>>(molr, mol, mol2rxn, feat, M);

    // ---- MLP head: tiled GEMMs ----
    fc_gemm_kernel<<<dim3(8, 16), 256, 0, stream>>>(feat, w_fc1, b_fc1, prelu1, hm, 1024, 512, 128, 1);
    fc_gemm_kernel<<<dim3(11, 16), 256, 0, stream>>>(hm, w_fc2, b_fc2, nullptr, (float*)d_out, 1024, 703, 512, 0);
}